// Round 3
// baseline (592.135 us; speedup 1.0000x reference)
//
#include <hip/hip_runtime.h>
#include <math.h>

#define NB 4      // batch
#define NP 144    // output spatial positions (12x12)
#define KW 9      // kernel window (3x3)
#define CIN 32
#define NC 32     // output capsules
#define NK 288    // KW*CIN children
#define ND 16     // pose dims
#define EPSI 1e-7f
#define NT 1024
#define NSL 32        // k-slices (NT/32)
#define KPT (NK/NSL)  // 9 k per thread
#define NWAVE 16
#define NRED 8        // s_red groups (waves 0-7 write, 8-15 add)

// One block per (b,p), 1024 threads = 16 waves -> 2 blocks/CU hits the
// 32-waves/CU cap (8 waves/SIMD, the max) with the fixed 576-block grid.
// c = t&31 (parent capsule), s = t>>5 (k-slice 0..31), 9 k per thread.
// it=0 peeled; E-step fused into next M-step; per-iter stats in registers.

__device__ __forceinline__ void load16(const float* src, float* dst) {
    const float4* s4 = (const float4*)src;
    *(float4*)&dst[0]  = s4[0];
    *(float4*)&dst[4]  = s4[1];
    *(float4*)&dst[8]  = s4[2];
    *(float4*)&dst[12] = s4[3];
}

__device__ __forceinline__ void vote44(const float* pr, const float* wr, float* vote) {
    #pragma unroll
    for (int i = 0; i < 4; ++i) {
        #pragma unroll
        for (int l = 0; l < 4; ++l) {
            float v = pr[i*4+0] * wr[0*4+l];
            v = fmaf(pr[i*4+1], wr[1*4+l], v);
            v = fmaf(pr[i*4+2], wr[2*4+l], v);
            v = fmaf(pr[i*4+3], wr[3*4+l], v);
            vote[i*4+l] = v;
        }
    }
}

__device__ __forceinline__ void reduce_finalize(
    float r0, float m1[ND], float m2[ND],
    int t, int c, int wave, int lane, float inv_temp,
    float (&s_red)[NRED][NC][34],
    float (&s_mu)[NC][17], float (&s_ivar)[NC][17], float (&s_lvar)[NC][17],
    float (&s_logout)[NC], float (&s_logdet)[NC], float (&s_outa)[NC],
    const float* __restrict__ g_beta_a, const float* __restrict__ g_beta_v)
{
    // merge s-pairs within each wave
    r0 += __shfl_xor(r0, 32);
    #pragma unroll
    for (int d = 0; d < ND; ++d) {
        m1[d] += __shfl_xor(m1[d], 32);
        m2[d] += __shfl_xor(m2[d], 32);
    }
    __syncthreads();                       // prior-pass s_red readers done
    if (lane < 32 && wave < NRED) {
        #pragma unroll
        for (int d = 0; d < ND; ++d) {
            s_red[wave][c][d]      = m1[d];
            s_red[wave][c][ND + d] = m2[d];
        }
        s_red[wave][c][32] = r0;
    }
    __syncthreads();
    if (lane < 32 && wave >= NRED) {
        #pragma unroll
        for (int d = 0; d < ND; ++d) {
            s_red[wave - NRED][c][d]      += m1[d];
            s_red[wave - NRED][c][ND + d] += m2[d];
        }
        s_red[wave - NRED][c][32] += r0;
    }
    __syncthreads();

    // finalize mu/var: one (c,d) per thread for t < 512
    if (t < NC * ND) {
        const int cc = t >> 4;
        const int d  = t & 15;
        float am1 = 0.0f, am2 = 0.0f, ar0s = 0.0f;
        #pragma unroll
        for (int g = 0; g < NRED; ++g) {
            am1  += s_red[g][cc][d];
            am2  += s_red[g][cc][ND + d];
            ar0s += s_red[g][cc][32];
        }
        const float rs  = ar0s + EPSI;
        const float mu  = am1 / rs;
        // sum rp*(v-mu)^2 = m2 - 2*mu*m1 + mu^2*r0  (exact expansion)
        const float var = (am2 - mu * (2.0f * am1 - mu * ar0s)) / rs + EPSI;
        s_mu[cc][d]   = mu;
        s_ivar[cc][d] = 1.0f / var;
        s_lvar[cc][d] = __logf(var);
    }
    __syncthreads();

    if (t < NC) {
        const float log2pi16 = 16.0f * 1.8378770664093453f;
        float ar0s = 0.0f;
        #pragma unroll
        for (int g = 0; g < NRED; ++g) ar0s += s_red[g][t][32];
        const float rs = ar0s + EPSI;
        float L = 0.0f;
        #pragma unroll
        for (int d = 0; d < ND; ++d) L += s_lvar[t][d];
        const float costsum = rs * (16.0f * g_beta_v[t] + 0.5f * L);
        const float x  = inv_temp * (g_beta_a[t] - costsum);
        const float oa = 1.0f / (1.0f + __expf(-x));
        s_outa[t]   = oa;
        s_logout[t] = __logf(oa + EPSI);
        s_logdet[t] = log2pi16 + L;
    }
    __syncthreads();
}

__global__ __launch_bounds__(NT, 8) void convcaps_em_kernel(
    const float* __restrict__ g_act,    // [B,196,32]
    const float* __restrict__ g_pose,   // [B,196,32,16]
    const float* __restrict__ g_W,      // [288,32,16]
    const float* __restrict__ g_beta_a, // [32]
    const float* __restrict__ g_beta_v, // [32]
    const int*   __restrict__ g_cpm,    // [144,9]
    float* __restrict__ g_out)          // act [B*144*32] then pose [B*144*32*16]
{
    __shared__ float s_pose[NK][ND];      // 18432 B
    __shared__ float s_act[NK];           // 1152 B
    __shared__ float s_red[NRED][NC][34]; // 34816 B
    __shared__ float s_mu[NC][17];        // 2176 B
    __shared__ float s_ivar[NC][17];
    __shared__ float s_lvar[NC][17];
    __shared__ float s_logout[NC];
    __shared__ float s_logdet[NC];
    __shared__ float s_outa[NC];
    __shared__ int   s_win[KW];

    const int bp   = blockIdx.x;
    const int b    = bp / NP;
    const int p    = bp - b * NP;
    const int t    = threadIdx.x;
    const int c    = t & 31;
    const int s    = t >> 5;
    const int wave = t >> 6;
    const int lane = t & 63;

    if (t < KW) s_win[t] = g_cpm[p * KW + t];
    __syncthreads();

    // ---- gather child poses + activations into LDS ----
    {
        const float* pb = g_pose + (size_t)b * (196 * CIN * ND);
        float* sp = &s_pose[0][0];
        for (int e = t; e < NK * ND; e += NT) {     // 4608 floats
            const int w   = e >> 9;                 // CIN*ND = 512
            const int rem = e & 511;
            sp[e] = pb[s_win[w] * (CIN * ND) + rem];
        }
        const float* ab = g_act + (size_t)b * (196 * CIN);
        if (t < NK) {
            const int w  = t >> 5;
            const int ci = t & 31;
            s_act[t] = ab[s_win[w] * CIN + ci];
        }
    }
    __syncthreads();

    const int    k0  = s * KPT;
    const float* wp0 = g_W + (size_t)(k0 * NC + c) * ND;

    // ================= pass 0: uniform rr = 1/32 =================
    {
        float r0 = 0.0f, m1[ND], m2[ND];
        #pragma unroll
        for (int d = 0; d < ND; ++d) { m1[d] = 0.0f; m2[d] = 0.0f; }

        const float* wp = wp0;
        for (int j = 0; j < KPT; ++j, wp += NC * ND) {
            const int k = k0 + j;
            float pr[ND], wr[ND], vote[ND];
            load16(&s_pose[k][0], pr);
            load16(wp, wr);
            vote44(pr, wr, vote);

            const float rp = s_act[k] * (1.0f / 32.0f);
            r0 += rp;
            #pragma unroll
            for (int d = 0; d < ND; ++d) {
                const float rv = rp * vote[d];
                m1[d] += rv;
                m2[d] = fmaf(rv, vote[d], m2[d]);
            }
        }
        reduce_finalize(r0, m1, m2, t, c, wave, lane, 1.0f,
                        s_red, s_mu, s_ivar, s_lvar, s_logout, s_logdet, s_outa,
                        g_beta_a, g_beta_v);
    }

    // ================= passes 1,2: E-step fused into M-step =================
    for (int it = 1; it < 3; ++it) {
        float mu_r[ND], iv_r[ND];
        #pragma unroll
        for (int d = 0; d < ND; ++d) { mu_r[d] = s_mu[c][d]; iv_r[d] = s_ivar[c][d]; }
        const float A = s_logout[c] - 0.5f * s_logdet[c];

        float r0 = 0.0f, m1[ND], m2[ND];
        #pragma unroll
        for (int d = 0; d < ND; ++d) { m1[d] = 0.0f; m2[d] = 0.0f; }

        const float* wp = wp0;
        for (int j = 0; j < KPT; ++j, wp += NC * ND) {
            const int k = k0 + j;
            float pr[ND], wr[ND], vote[ND];
            load16(&s_pose[k][0], pr);
            load16(wp, wr);
            vote44(pr, wr, vote);

            float q = 0.0f;
            #pragma unroll
            for (int d = 0; d < ND; ++d) {
                const float diff = vote[d] - mu_r[d];
                q = fmaf(diff * diff, iv_r[d], q);
            }
            float logit = A - 0.5f * q;

            // softmax over the 32 c's = 32 lanes of this half-wave
            float mx = logit;
            mx = fmaxf(mx, __shfl_xor(mx, 16));
            mx = fmaxf(mx, __shfl_xor(mx, 8));
            mx = fmaxf(mx, __shfl_xor(mx, 4));
            mx = fmaxf(mx, __shfl_xor(mx, 2));
            mx = fmaxf(mx, __shfl_xor(mx, 1));
            const float e = __expf(logit - mx);
            float se = e;
            se += __shfl_xor(se, 16);
            se += __shfl_xor(se, 8);
            se += __shfl_xor(se, 4);
            se += __shfl_xor(se, 2);
            se += __shfl_xor(se, 1);
            const float rr = e / se;

            const float rp = rr * s_act[k];
            r0 += rp;
            #pragma unroll
            for (int d = 0; d < ND; ++d) {
                const float rv = rp * vote[d];
                m1[d] += rv;
                m2[d] = fmaf(rv, vote[d], m2[d]);
            }
        }
        reduce_finalize(r0, m1, m2, t, c, wave, lane, 1.0f + (float)it,
                        s_red, s_mu, s_ivar, s_lvar, s_logout, s_logdet, s_outa,
                        g_beta_a, g_beta_v);
    }

    // ---- write outputs: act [B,P,C] then pose [B,P,C,16] ----
    const int base = (b * NP + p) * NC;
    if (t < NC) g_out[base + t] = s_outa[t];
    float* outpose = g_out + NB * NP * NC;
    if (t < NC * ND) {
        const int cc = t >> 4;
        const int d  = t & 15;
        outpose[(size_t)(base + cc) * ND + d] = s_mu[cc][d];
    }
}

extern "C" void kernel_launch(void* const* d_in, const int* in_sizes, int n_in,
                              void* d_out, int out_size, void* d_ws, size_t ws_size,
                              hipStream_t stream) {
    const float* in_act  = (const float*)d_in[0];
    const float* in_pose = (const float*)d_in[1];
    const float* W       = (const float*)d_in[2];
    const float* beta_a  = (const float*)d_in[3];
    const float* beta_v  = (const float*)d_in[4];
    const int*   cpm     = (const int*)d_in[5];
    float* out = (float*)d_out;

    convcaps_em_kernel<<<dim3(NB * NP), dim3(NT), 0, stream>>>(
        in_act, in_pose, W, beta_a, beta_v, cpm, out);
}

// Round 4
// 240.866 us; speedup vs baseline: 2.4584x; 2.4584x over previous
//
#include <hip/hip_runtime.h>
#include <math.h>

#define NB 4      // batch
#define NP 144    // output spatial positions (12x12)
#define KW 9      // kernel window (3x3)
#define CIN 32
#define NC 32     // output capsules
#define NK 288    // KW*CIN children
#define ND 16     // pose dims
#define EPSI 1e-7f
#define NT 512
#define NSL 16        // k-slices
#define KPT 18        // NK/NSL, k per thread
#define NWAVES 8

// One block per (b,p). c = t&31, s = t>>5 (k-slice), 18 k per thread.
// launch_bounds(512,4): 128-VGPR cap — round 3 showed <=64 regs spills 2GB.
// E-step fused into next M-step; 2-k manual interleave hides shfl latency.
// Reduction: single write phase into split arrays, 3 barriers per pass.

__device__ __forceinline__ void load16(const float* src, float* dst) {
    const float4* s4 = (const float4*)src;
    *(float4*)&dst[0]  = s4[0];
    *(float4*)&dst[4]  = s4[1];
    *(float4*)&dst[8]  = s4[2];
    *(float4*)&dst[12] = s4[3];
}

__device__ __forceinline__ void vote44(const float* pr, const float* wr, float* vote) {
    #pragma unroll
    for (int i = 0; i < 4; ++i) {
        #pragma unroll
        for (int l = 0; l < 4; ++l) {
            float v = pr[i*4+0] * wr[0*4+l];
            v = fmaf(pr[i*4+1], wr[1*4+l], v);
            v = fmaf(pr[i*4+2], wr[2*4+l], v);
            v = fmaf(pr[i*4+3], wr[3*4+l], v);
            vote[i*4+l] = v;
        }
    }
}

__device__ __forceinline__ void reduce_finalize(
    float r0, float m1[ND], float m2[ND],
    int t, int c, int wave, int lane, float inv_temp,
    float rbeta_a, float rbeta_v,
    float (&s_m1)[NWAVES][NC][ND], float (&s_m2)[NWAVES][NC][ND], float (&s_r0)[NWAVES][NC],
    float (&s_mu)[NC][17], float (&s_ivar)[NC][17],
    float (&s_L)[NC], float (&s_A)[NC], float (&s_outa)[NC])
{
    // merge the two halves of each wave (s and s+1 slices share lanes mod 32)
    r0 += __shfl_xor(r0, 32);
    #pragma unroll
    for (int d = 0; d < ND; ++d) {
        m1[d] += __shfl_xor(m1[d], 32);
        m2[d] += __shfl_xor(m2[d], 32);
    }
    // single write phase: each wave owns its s_red group. Prior-pass readers of
    // these arrays are protected by the previous pass's trailing barriers.
    if (lane < 32) {
        float4* d1 = (float4*)&s_m1[wave][c][0];
        d1[0] = *(const float4*)&m1[0];
        d1[1] = *(const float4*)&m1[4];
        d1[2] = *(const float4*)&m1[8];
        d1[3] = *(const float4*)&m1[12];
        float4* d2 = (float4*)&s_m2[wave][c][0];
        d2[0] = *(const float4*)&m2[0];
        d2[1] = *(const float4*)&m2[4];
        d2[2] = *(const float4*)&m2[8];
        d2[3] = *(const float4*)&m2[12];
        s_r0[wave][c] = r0;
    }
    __syncthreads();

    // finalize: every thread owns one (cc,d) — NT == NC*ND == 512
    {
        const int cc = t >> 4;
        const int d  = t & 15;
        float am1 = 0.0f, am2 = 0.0f, ar0 = 0.0f;
        #pragma unroll
        for (int g = 0; g < NWAVES; ++g) {
            am1 += s_m1[g][cc][d];
            am2 += s_m2[g][cc][d];
            ar0 += s_r0[g][cc];
        }
        const float rs  = ar0 + EPSI;
        const float irs = __builtin_amdgcn_rcpf(rs);
        const float mu  = am1 * irs;
        // sum rp*(v-mu)^2 = m2 - 2*mu*m1 + mu^2*r0  (exact expansion)
        const float var = (am2 - mu * (2.0f * am1 - mu * ar0)) * irs + EPSI;
        const float lv  = __logf(var);
        s_mu[cc][d]   = mu;
        s_ivar[cc][d] = __builtin_amdgcn_rcpf(var);
        // sum lv over d (low 4 lane bits) in-register
        float Ls = lv;
        Ls += __shfl_xor(Ls, 1);
        Ls += __shfl_xor(Ls, 2);
        Ls += __shfl_xor(Ls, 4);
        Ls += __shfl_xor(Ls, 8);
        if (d == 0) s_L[cc] = Ls;
    }
    __syncthreads();

    if (t < NC) {
        const float log2pi16 = 16.0f * 1.8378770664093453f;
        float ar0 = 0.0f;
        #pragma unroll
        for (int g = 0; g < NWAVES; ++g) ar0 += s_r0[g][t];
        const float rs = ar0 + EPSI;
        const float L  = s_L[t];
        const float costsum = rs * (16.0f * rbeta_v + 0.5f * L);
        const float x  = inv_temp * (rbeta_a - costsum);
        const float oa = 1.0f / (1.0f + __expf(-x));
        s_outa[t] = oa;
        // combined logit base for next E-step: log(oa+eps) - 0.5*logdet
        s_A[t] = __logf(oa + EPSI) - 0.5f * (log2pi16 + L);
    }
    __syncthreads();
}

__global__ __launch_bounds__(NT, 4) void convcaps_em_kernel(
    const float* __restrict__ g_act,    // [B,196,32]
    const float* __restrict__ g_pose,   // [B,196,32,16]
    const float* __restrict__ g_W,      // [288,32,16]
    const float* __restrict__ g_beta_a, // [32]
    const float* __restrict__ g_beta_v, // [32]
    const int*   __restrict__ g_cpm,    // [144,9]
    float* __restrict__ g_out)          // act [B*144*32] then pose [B*144*32*16]
{
    __shared__ float s_pose[NK][ND];         // 18432 B
    __shared__ float s_act[NK];              // 1152 B
    __shared__ float s_m1[NWAVES][NC][ND];   // 16384 B
    __shared__ float s_m2[NWAVES][NC][ND];   // 16384 B
    __shared__ float s_r0[NWAVES][NC];       // 1024 B
    __shared__ float s_mu[NC][17];           // 2176 B
    __shared__ float s_ivar[NC][17];         // 2176 B
    __shared__ float s_L[NC];
    __shared__ float s_A[NC];
    __shared__ float s_outa[NC];
    __shared__ int   s_win[KW];              // total ~58 KB -> 2 blocks/CU

    const int bp   = blockIdx.x;
    const int b    = bp / NP;
    const int p    = bp - b * NP;
    const int t    = threadIdx.x;
    const int c    = t & 31;
    const int s    = t >> 5;
    const int wave = t >> 6;
    const int lane = t & 63;

    float rbeta_a = 0.0f, rbeta_v = 0.0f;
    if (t < KW) s_win[t] = g_cpm[p * KW + t];
    if (t < NC) { rbeta_a = g_beta_a[t]; rbeta_v = g_beta_v[t]; }
    __syncthreads();

    // ---- gather child poses (float4) + activations into LDS ----
    {
        const float4* pb4 = (const float4*)(g_pose + (size_t)b * (196 * CIN * ND));
        float4* sp4 = (float4*)&s_pose[0][0];
        for (int i4 = t; i4 < NK * ND / 4; i4 += NT) {  // 1152 float4
            const int w   = i4 >> 7;                    // 128 float4 per window
            const int rem = i4 & 127;
            sp4[i4] = pb4[(size_t)s_win[w] * 128 + rem];
        }
        const float* ab = g_act + (size_t)b * (196 * CIN);
        if (t < NK) s_act[t] = ab[s_win[t >> 5] * CIN + (t & 31)];
    }
    __syncthreads();

    const int    k0  = s * KPT;
    const float* wp0 = g_W + (size_t)(k0 * NC + c) * ND;

    // ================= pass 0: uniform rr = 1/32 =================
    {
        float r0 = 0.0f, m1[ND], m2[ND];
        #pragma unroll
        for (int d = 0; d < ND; ++d) { m1[d] = 0.0f; m2[d] = 0.0f; }

        const float* wp = wp0;
        for (int j = 0; j < KPT; ++j, wp += NC * ND) {
            const int k = k0 + j;
            float pr[ND], wr[ND], vote[ND];
            load16(&s_pose[k][0], pr);
            load16(wp, wr);
            vote44(pr, wr, vote);

            const float rp = s_act[k] * (1.0f / 32.0f);
            r0 += rp;
            #pragma unroll
            for (int d = 0; d < ND; ++d) {
                const float rv = rp * vote[d];
                m1[d] += rv;
                m2[d] = fmaf(rv, vote[d], m2[d]);
            }
        }
        reduce_finalize(r0, m1, m2, t, c, wave, lane, 1.0f, rbeta_a, rbeta_v,
                        s_m1, s_m2, s_r0, s_mu, s_ivar, s_L, s_A, s_outa);
    }

    // ================= passes 1,2: E-step fused, 2-k interleaved =================
    for (int it = 1; it < 3; ++it) {
        // hoist per-iteration stats: q = sum_d v*(iv*v - 2*iv*mu) + g; fold g into base
        float iv_r[ND], h2n_r[ND];
        float gq = 0.0f;
        #pragma unroll
        for (int d = 0; d < ND; ++d) {
            const float mu = s_mu[c][d];
            const float iv = s_ivar[c][d];
            iv_r[d] = iv;
            const float h = iv * mu;
            h2n_r[d] = -(h + h);
            gq = fmaf(h, mu, gq);
        }
        const float Abase = s_A[c] - 0.5f * gq;

        float r0 = 0.0f, m1[ND], m2[ND];
        #pragma unroll
        for (int d = 0; d < ND; ++d) { m1[d] = 0.0f; m2[d] = 0.0f; }

        const float* wp = wp0;
        for (int jj = 0; jj < KPT; jj += 2) {
            const int k1 = k0 + jj;
            const int k2 = k1 + 1;
            float v1[ND], v2[ND];
            {
                float pr[ND], wr[ND];
                load16(&s_pose[k1][0], pr);
                load16(wp, wr);
                vote44(pr, wr, v1);
            }
            wp += NC * ND;
            {
                float pr[ND], wr[ND];
                load16(&s_pose[k2][0], pr);
                load16(wp, wr);
                vote44(pr, wr, v2);
            }
            wp += NC * ND;

            float q1 = 0.0f, q2 = 0.0f;
            #pragma unroll
            for (int d = 0; d < ND; ++d) {
                const float t1 = fmaf(iv_r[d], v1[d], h2n_r[d]);
                q1 = fmaf(t1, v1[d], q1);
                const float t2 = fmaf(iv_r[d], v2[d], h2n_r[d]);
                q2 = fmaf(t2, v2[d], q2);
            }
            const float l1 = fmaf(-0.5f, q1, Abase);
            const float l2 = fmaf(-0.5f, q2, Abase);

            // two interleaved softmaxes over the 32 c-lanes of each half-wave
            float mx1 = l1, mx2 = l2;
            mx1 = fmaxf(mx1, __shfl_xor(mx1, 16)); mx2 = fmaxf(mx2, __shfl_xor(mx2, 16));
            mx1 = fmaxf(mx1, __shfl_xor(mx1, 8));  mx2 = fmaxf(mx2, __shfl_xor(mx2, 8));
            mx1 = fmaxf(mx1, __shfl_xor(mx1, 4));  mx2 = fmaxf(mx2, __shfl_xor(mx2, 4));
            mx1 = fmaxf(mx1, __shfl_xor(mx1, 2));  mx2 = fmaxf(mx2, __shfl_xor(mx2, 2));
            mx1 = fmaxf(mx1, __shfl_xor(mx1, 1));  mx2 = fmaxf(mx2, __shfl_xor(mx2, 1));
            float e1 = __expf(l1 - mx1), e2 = __expf(l2 - mx2);
            float se1 = e1, se2 = e2;
            se1 += __shfl_xor(se1, 16); se2 += __shfl_xor(se2, 16);
            se1 += __shfl_xor(se1, 8);  se2 += __shfl_xor(se2, 8);
            se1 += __shfl_xor(se1, 4);  se2 += __shfl_xor(se2, 4);
            se1 += __shfl_xor(se1, 2);  se2 += __shfl_xor(se2, 2);
            se1 += __shfl_xor(se1, 1);  se2 += __shfl_xor(se2, 1);

            const float rp1 = e1 * __builtin_amdgcn_rcpf(se1) * s_act[k1];
            const float rp2 = e2 * __builtin_amdgcn_rcpf(se2) * s_act[k2];
            r0 += rp1 + rp2;
            #pragma unroll
            for (int d = 0; d < ND; ++d) {
                const float rv1 = rp1 * v1[d];
                const float rv2 = rp2 * v2[d];
                m1[d] += rv1 + rv2;
                m2[d] = fmaf(rv1, v1[d], m2[d]);
                m2[d] = fmaf(rv2, v2[d], m2[d]);
            }
        }
        reduce_finalize(r0, m1, m2, t, c, wave, lane, 1.0f + (float)it, rbeta_a, rbeta_v,
                        s_m1, s_m2, s_r0, s_mu, s_ivar, s_L, s_A, s_outa);
    }

    // ---- write outputs: act [B,P,C] then pose [B,P,C,16] ----
    const int base = (b * NP + p) * NC;
    if (t < NC) g_out[base + t] = s_outa[t];
    float* outpose = g_out + NB * NP * NC;
    {
        const int cc = t >> 4;
        const int d  = t & 15;
        outpose[(size_t)(base + cc) * ND + d] = s_mu[cc][d];
    }
}

extern "C" void kernel_launch(void* const* d_in, const int* in_sizes, int n_in,
                              void* d_out, int out_size, void* d_ws, size_t ws_size,
                              hipStream_t stream) {
    const float* in_act  = (const float*)d_in[0];
    const float* in_pose = (const float*)d_in[1];
    const float* W       = (const float*)d_in[2];
    const float* beta_a  = (const float*)d_in[3];
    const float* beta_v  = (const float*)d_in[4];
    const int*   cpm     = (const int*)d_in[5];
    float* out = (float*)d_out;

    convcaps_em_kernel<<<dim3(NB * NP), dim3(NT), 0, stream>>>(
        in_act, in_pose, W, beta_a, beta_v, cpm, out);
}

// Round 5
// 111.470 us; speedup vs baseline: 5.3121x; 2.1608x over previous
//
#include <hip/hip_runtime.h>
#include <math.h>

#define NB 4      // batch
#define NP 144    // output spatial positions (12x12)
#define KW 9      // kernel window (3x3)
#define CIN 32
#define NC 32     // output capsules
#define NK 288    // KW*CIN children
#define ND 16     // pose dims
#define EPSI 1e-7f
#define NT 512
#define NSL 16        // k-slices
#define KPT 18        // k per thread
#define NWAVES 8

// One block per (b,p). c = t&31, s = t>>5 (k-slice), 18 k per thread.
// launch_bounds(512,2): empirical VGPR cap = 256/arg = 128 (r3/r4 evidence:
// arg=4 -> 64-cap spill, arg=8 -> 32-cap spill). Body needs ~110.
// Softmax reductions over the 32 c-lanes use DPP (VALU pipe) for xor1/2/4/8
// and one ds_swizzle for xor16 — 2 DS ops per k instead of 10.

template<int CTRL>
__device__ __forceinline__ float dppf(float x) {
    return __int_as_float(__builtin_amdgcn_update_dpp(
        0, __float_as_int(x), CTRL, 0xF, 0xF, true));
}
// 0xB1 = quad_perm(1,0,3,2) = xor1 ; 0x4E = quad_perm(2,3,0,1) = xor2
// 0x141 = row_half_mirror (xor7 == xor4 once 4-groups uniform)
// 0x140 = row_mirror      (xor15 == xor8 once 8-groups uniform)
__device__ __forceinline__ float swz16(float x) {
    return __int_as_float(__builtin_amdgcn_ds_swizzle(__float_as_int(x), 0x401F));
}
__device__ __forceinline__ float red32_max(float x) {
    x = fmaxf(x, dppf<0xB1>(x));
    x = fmaxf(x, dppf<0x4E>(x));
    x = fmaxf(x, dppf<0x141>(x));
    x = fmaxf(x, dppf<0x140>(x));
    x = fmaxf(x, swz16(x));
    return x;
}
__device__ __forceinline__ float red32_sum(float x) {
    x += dppf<0xB1>(x);
    x += dppf<0x4E>(x);
    x += dppf<0x141>(x);
    x += dppf<0x140>(x);
    x += swz16(x);
    return x;
}
__device__ __forceinline__ float red16_sum(float x) {  // sum over lane bits 0-3
    x += dppf<0xB1>(x);
    x += dppf<0x4E>(x);
    x += dppf<0x141>(x);
    x += dppf<0x140>(x);
    return x;
}

__device__ __forceinline__ void load16(const float* src, float* dst) {
    const float4* s4 = (const float4*)src;
    *(float4*)&dst[0]  = s4[0];
    *(float4*)&dst[4]  = s4[1];
    *(float4*)&dst[8]  = s4[2];
    *(float4*)&dst[12] = s4[3];
}

__device__ __forceinline__ void vote44(const float* pr, const float* wr, float* vote) {
    #pragma unroll
    for (int i = 0; i < 4; ++i) {
        #pragma unroll
        for (int l = 0; l < 4; ++l) {
            float v = pr[i*4+0] * wr[0*4+l];
            v = fmaf(pr[i*4+1], wr[1*4+l], v);
            v = fmaf(pr[i*4+2], wr[2*4+l], v);
            v = fmaf(pr[i*4+3], wr[3*4+l], v);
            vote[i*4+l] = v;
        }
    }
}

__device__ __forceinline__ void reduce_finalize(
    float r0, float m1[ND], float m2[ND],
    int t, int c, int wave, int lane, float inv_temp,
    float rbeta_a, float rbeta_v,
    float (&s_m1)[NWAVES][NC][ND], float (&s_m2)[NWAVES][NC][ND], float (&s_r0)[NWAVES][NC],
    float (&s_mu)[NC][17], float (&s_ivar)[NC][17],
    float (&s_L)[NC], float (&s_A)[NC], float (&s_outa)[NC])
{
    // merge the two k-slices within each wave
    r0 += __shfl_xor(r0, 32);
    #pragma unroll
    for (int d = 0; d < ND; ++d) {
        m1[d] += __shfl_xor(m1[d], 32);
        m2[d] += __shfl_xor(m2[d], 32);
    }
    // single write phase; prior-pass readers protected by trailing barriers below
    if (lane < 32) {
        float4* d1 = (float4*)&s_m1[wave][c][0];
        d1[0] = *(const float4*)&m1[0];
        d1[1] = *(const float4*)&m1[4];
        d1[2] = *(const float4*)&m1[8];
        d1[3] = *(const float4*)&m1[12];
        float4* d2 = (float4*)&s_m2[wave][c][0];
        d2[0] = *(const float4*)&m2[0];
        d2[1] = *(const float4*)&m2[4];
        d2[2] = *(const float4*)&m2[8];
        d2[3] = *(const float4*)&m2[12];
        s_r0[wave][c] = r0;
    }
    __syncthreads();

    // finalize: each thread owns one (cc,d)  (NT == NC*ND == 512)
    {
        const int cc = t >> 4;
        const int d  = t & 15;
        float am1 = 0.0f, am2 = 0.0f, ar0 = 0.0f;
        #pragma unroll
        for (int g = 0; g < NWAVES; ++g) {
            am1 += s_m1[g][cc][d];
            am2 += s_m2[g][cc][d];
            ar0 += s_r0[g][cc];
        }
        const float rs  = ar0 + EPSI;
        const float irs = __builtin_amdgcn_rcpf(rs);
        const float mu  = am1 * irs;
        // sum rp*(v-mu)^2 = m2 - 2*mu*m1 + mu^2*r0  (exact expansion)
        const float var = (am2 - mu * (2.0f * am1 - mu * ar0)) * irs + EPSI;
        const float lv  = __logf(var);
        s_mu[cc][d]   = mu;
        s_ivar[cc][d] = __builtin_amdgcn_rcpf(var);
        const float Ls = red16_sum(lv);      // sum over d (lane bits 0-3)
        if (d == 0) s_L[cc] = Ls;
    }
    __syncthreads();

    if (t < NC) {
        const float log2pi16 = 16.0f * 1.8378770664093453f;
        float ar0 = 0.0f;
        #pragma unroll
        for (int g = 0; g < NWAVES; ++g) ar0 += s_r0[g][t];
        const float rs = ar0 + EPSI;
        const float L  = s_L[t];
        const float costsum = rs * (16.0f * rbeta_v + 0.5f * L);
        const float x  = inv_temp * (rbeta_a - costsum);
        const float oa = 1.0f / (1.0f + __expf(-x));
        s_outa[t] = oa;
        // combined logit base for next E-step: log(oa+eps) - 0.5*logdet
        s_A[t] = __logf(oa + EPSI) - 0.5f * (log2pi16 + L);
    }
    __syncthreads();
}

__global__ __launch_bounds__(NT, 2) void convcaps_em_kernel(
    const float* __restrict__ g_act,    // [B,196,32]
    const float* __restrict__ g_pose,   // [B,196,32,16]
    const float* __restrict__ g_W,      // [288,32,16]
    const float* __restrict__ g_beta_a, // [32]
    const float* __restrict__ g_beta_v, // [32]
    const int*   __restrict__ g_cpm,    // [144,9]
    float* __restrict__ g_out)          // act [B*144*32] then pose [B*144*32*16]
{
    __shared__ float s_pose[NK][ND];         // 18432 B
    __shared__ float s_act[NK];              // 1152 B
    __shared__ float s_m1[NWAVES][NC][ND];   // 16384 B
    __shared__ float s_m2[NWAVES][NC][ND];   // 16384 B
    __shared__ float s_r0[NWAVES][NC];       // 1024 B
    __shared__ float s_mu[NC][17];           // 2176 B
    __shared__ float s_ivar[NC][17];         // 2176 B
    __shared__ float s_L[NC];
    __shared__ float s_A[NC];
    __shared__ float s_outa[NC];
    __shared__ int   s_win[KW];              // ~58 KB -> 2 blocks/CU

    const int bp   = blockIdx.x;
    const int b    = bp / NP;
    const int p    = bp - b * NP;
    const int t    = threadIdx.x;
    const int c    = t & 31;
    const int s    = t >> 5;
    const int wave = t >> 6;
    const int lane = t & 63;

    float rbeta_a = 0.0f, rbeta_v = 0.0f;
    if (t < KW) s_win[t] = g_cpm[p * KW + t];
    if (t < NC) { rbeta_a = g_beta_a[t]; rbeta_v = g_beta_v[t]; }
    __syncthreads();

    // ---- gather child poses (float4) + activations into LDS ----
    {
        const float4* pb4 = (const float4*)(g_pose + (size_t)b * (196 * CIN * ND));
        float4* sp4 = (float4*)&s_pose[0][0];
        for (int i4 = t; i4 < NK * ND / 4; i4 += NT) {  // 1152 float4
            const int w   = i4 >> 7;                    // 128 float4 per window
            const int rem = i4 & 127;
            sp4[i4] = pb4[(size_t)s_win[w] * 128 + rem];
        }
        const float* ab = g_act + (size_t)b * (196 * CIN);
        if (t < NK) s_act[t] = ab[s_win[t >> 5] * CIN + (t & 31)];
    }
    __syncthreads();

    const int    k0  = s * KPT;
    const float* wp0 = g_W + (size_t)(k0 * NC + c) * ND;

    // ================= pass 0: uniform rr = 1/32 =================
    {
        float r0 = 0.0f, m1[ND], m2[ND];
        #pragma unroll
        for (int d = 0; d < ND; ++d) { m1[d] = 0.0f; m2[d] = 0.0f; }

        const float* wp = wp0;
        for (int j = 0; j < KPT; ++j, wp += NC * ND) {
            const int k = k0 + j;
            float pr[ND], wr[ND], vote[ND];
            load16(&s_pose[k][0], pr);
            load16(wp, wr);
            vote44(pr, wr, vote);

            const float rp = s_act[k] * (1.0f / 32.0f);
            r0 += rp;
            #pragma unroll
            for (int d = 0; d < ND; ++d) {
                const float rv = rp * vote[d];
                m1[d] += rv;
                m2[d] = fmaf(rv, vote[d], m2[d]);
            }
        }
        reduce_finalize(r0, m1, m2, t, c, wave, lane, 1.0f, rbeta_a, rbeta_v,
                        s_m1, s_m2, s_r0, s_mu, s_ivar, s_L, s_A, s_outa);
    }

    // ================= passes 1,2: E-step fused into M-step =================
    for (int it = 1; it < 3; ++it) {
        // hoist per-iteration stats: q = sum_d v*(iv*v - 2*iv*mu) + g; fold g into base
        float iv_r[ND], h2n_r[ND];
        float gq = 0.0f;
        #pragma unroll
        for (int d = 0; d < ND; ++d) {
            const float mu = s_mu[c][d];
            const float iv = s_ivar[c][d];
            iv_r[d] = iv;
            const float h = iv * mu;
            h2n_r[d] = -(h + h);
            gq = fmaf(h, mu, gq);
        }
        const float Abase = s_A[c] - 0.5f * gq;

        float r0 = 0.0f, m1[ND], m2[ND];
        #pragma unroll
        for (int d = 0; d < ND; ++d) { m1[d] = 0.0f; m2[d] = 0.0f; }

        const float* wp = wp0;
        for (int j = 0; j < KPT; ++j, wp += NC * ND) {
            const int k = k0 + j;
            float pr[ND], wr[ND], v[ND];
            load16(&s_pose[k][0], pr);
            load16(wp, wr);
            vote44(pr, wr, v);

            float q = 0.0f;
            #pragma unroll
            for (int d = 0; d < ND; ++d) {
                const float tq = fmaf(iv_r[d], v[d], h2n_r[d]);
                q = fmaf(tq, v[d], q);
            }
            const float logit = fmaf(-0.5f, q, Abase);

            // softmax over the 32 c-lanes: DPP + one swizzle per reduce
            const float mx = red32_max(logit);
            const float e  = __expf(logit - mx);
            const float se = red32_sum(e);

            const float rp = e * __builtin_amdgcn_rcpf(se) * s_act[k];
            r0 += rp;
            #pragma unroll
            for (int d = 0; d < ND; ++d) {
                const float rv = rp * v[d];
                m1[d] += rv;
                m2[d] = fmaf(rv, v[d], m2[d]);
            }
        }
        reduce_finalize(r0, m1, m2, t, c, wave, lane, 1.0f + (float)it, rbeta_a, rbeta_v,
                        s_m1, s_m2, s_r0, s_mu, s_ivar, s_L, s_A, s_outa);
    }

    // ---- write outputs: act [B,P,C] then pose [B,P,C,16] ----
    const int base = (b * NP + p) * NC;
    if (t < NC) g_out[base + t] = s_outa[t];
    float* outpose = g_out + NB * NP * NC;
    {
        const int cc = t >> 4;
        const int d  = t & 15;
        outpose[(size_t)(base + cc) * ND + d] = s_mu[cc][d];
    }
}

extern "C" void kernel_launch(void* const* d_in, const int* in_sizes, int n_in,
                              void* d_out, int out_size, void* d_ws, size_t ws_size,
                              hipStream_t stream) {
    const float* in_act  = (const float*)d_in[0];
    const float* in_pose = (const float*)d_in[1];
    const float* W       = (const float*)d_in[2];
    const float* beta_a  = (const float*)d_in[3];
    const float* beta_v  = (const float*)d_in[4];
    const int*   cpm     = (const int*)d_in[5];
    float* out = (float*)d_out;

    convcaps_em_kernel<<<dim3(NB * NP), dim3(NT), 0, stream>>>(
        in_act, in_pose, W, beta_a, beta_v, cpm, out);
}

// Round 6
// 111.391 us; speedup vs baseline: 5.3158x; 1.0007x over previous
//
#include <hip/hip_runtime.h>
#include <math.h>

#define NB 4      // batch
#define NP 144    // output spatial positions (12x12)
#define KW 9      // kernel window (3x3)
#define CIN 32
#define NC 32     // output capsules
#define NK 288    // KW*CIN children
#define ND 16     // pose dims
#define EPSI 1e-7f
#define NT 512
#define KPT 18        // k per thread
#define NRED 4        // reduction groups (waves 4-7 write, 0-3 add)

// One block per (b,p). c = t&31, s = t>>5 (k-slice), 18 k per thread.
// LDS = exactly 40960 B -> 4 blocks/CU -> all 576 blocks resident (no tail),
// 8 waves/SIMD during the main loop. launch_bounds(512,2): empirical VGPR
// cap = 256/arg = 128 (r3: arg=8 -> 32-cap spill; r4: arg=4 -> 64-cap spill).
// Softmax over the 32 c-lanes: DPP for xor1/2/4/8 + one ds_swizzle for xor16.

template<int CTRL>
__device__ __forceinline__ float dppf(float x) {
    return __int_as_float(__builtin_amdgcn_update_dpp(
        0, __float_as_int(x), CTRL, 0xF, 0xF, true));
}
// 0xB1=quad_perm xor1 ; 0x4E=quad_perm xor2 ; 0x141=row_half_mirror (xor4 once
// 4-uniform) ; 0x140=row_mirror (xor8 once 8-uniform)
__device__ __forceinline__ float swz16(float x) {
    return __int_as_float(__builtin_amdgcn_ds_swizzle(__float_as_int(x), 0x401F));
}
__device__ __forceinline__ float red32_max(float x) {
    x = fmaxf(x, dppf<0xB1>(x));
    x = fmaxf(x, dppf<0x4E>(x));
    x = fmaxf(x, dppf<0x141>(x));
    x = fmaxf(x, dppf<0x140>(x));
    x = fmaxf(x, swz16(x));
    return x;
}
__device__ __forceinline__ float red32_sum(float x) {
    x += dppf<0xB1>(x);
    x += dppf<0x4E>(x);
    x += dppf<0x141>(x);
    x += dppf<0x140>(x);
    x += swz16(x);
    return x;
}
__device__ __forceinline__ float red16_sum(float x) {  // sum over lane bits 0-3
    x += dppf<0xB1>(x);
    x += dppf<0x4E>(x);
    x += dppf<0x141>(x);
    x += dppf<0x140>(x);
    return x;
}

__device__ __forceinline__ int sw4(int c, int j) { return j ^ ((c >> 1) & 3); }

__device__ __forceinline__ void load16(const float* src, float* dst) {
    const float4* s4 = (const float4*)src;
    *(float4*)&dst[0]  = s4[0];
    *(float4*)&dst[4]  = s4[1];
    *(float4*)&dst[8]  = s4[2];
    *(float4*)&dst[12] = s4[3];
}

__device__ __forceinline__ void vote44(const float* pr, const float* wr, float* vote) {
    #pragma unroll
    for (int i = 0; i < 4; ++i) {
        #pragma unroll
        for (int l = 0; l < 4; ++l) {
            float v = pr[i*4+0] * wr[0*4+l];
            v = fmaf(pr[i*4+1], wr[1*4+l], v);
            v = fmaf(pr[i*4+2], wr[2*4+l], v);
            v = fmaf(pr[i*4+3], wr[3*4+l], v);
            vote[i*4+l] = v;
        }
    }
}

__device__ __forceinline__ void reduce_finalize(
    float r0, float m1[ND], float m2[ND],
    int t, int c, int wave, int lane, float inv_temp, bool last,
    float rbeta_a, float rbeta_v,
    float (&s_m1)[NRED][NC][ND], float (&s_m2)[NRED][NC][ND], float (&s_r0)[NRED][NC],
    float (&s_mu)[NC][17], float (&s_ivar)[NC][17], float (&s_A)[NC])
{
    // merge the two k-slices within each wave
    r0 += __shfl_xor(r0, 32);
    #pragma unroll
    for (int d = 0; d < ND; ++d) {
        m1[d] += __shfl_xor(m1[d], 32);
        m2[d] += __shfl_xor(m2[d], 32);
    }
    // stage 1: waves 4-7 write their group (swizzled float4 -> 4-cy b128)
    if (lane < 32 && wave >= NRED) {
        float4* d1 = (float4*)&s_m1[wave - NRED][c][0];
        float4* d2 = (float4*)&s_m2[wave - NRED][c][0];
        #pragma unroll
        for (int j = 0; j < 4; ++j) {
            d1[sw4(c, j)] = *(const float4*)&m1[4*j];
            d2[sw4(c, j)] = *(const float4*)&m2[4*j];
        }
        s_r0[wave - NRED][c] = r0;
    }
    __syncthreads();
    // stage 2: waves 0-3 add into their group
    if (lane < 32 && wave < NRED) {
        float4* d1 = (float4*)&s_m1[wave][c][0];
        float4* d2 = (float4*)&s_m2[wave][c][0];
        #pragma unroll
        for (int j = 0; j < 4; ++j) {
            float4 v1 = d1[sw4(c, j)];
            v1.x += m1[4*j]; v1.y += m1[4*j+1]; v1.z += m1[4*j+2]; v1.w += m1[4*j+3];
            d1[sw4(c, j)] = v1;
            float4 v2 = d2[sw4(c, j)];
            v2.x += m2[4*j]; v2.y += m2[4*j+1]; v2.z += m2[4*j+2]; v2.w += m2[4*j+3];
            d2[sw4(c, j)] = v2;
        }
        s_r0[wave][c] += r0;
    }
    __syncthreads();

    // finalize: each thread owns one (cc,d)  (NT == NC*ND == 512)
    {
        const int cc = t >> 4;
        const int d  = t & 15;
        const int fi = cc * ND + sw4(cc, d >> 2) * 4 + (d & 3);
        float am1 = 0.0f, am2 = 0.0f, ar0 = 0.0f;
        #pragma unroll
        for (int g = 0; g < NRED; ++g) {
            am1 += (&s_m1[g][0][0])[fi];
            am2 += (&s_m2[g][0][0])[fi];
            ar0 += s_r0[g][cc];
        }
        const float rs  = ar0 + EPSI;
        const float irs = __builtin_amdgcn_rcpf(rs);
        const float mu  = am1 * irs;
        // sum rp*(v-mu)^2 = m2 - 2*mu*m1 + mu^2*r0  (exact expansion)
        const float var = (am2 - mu * (2.0f * am1 - mu * ar0)) * irs + EPSI;
        const float lv  = __logf(var);
        s_mu[cc][d]   = mu;
        s_ivar[cc][d] = __builtin_amdgcn_rcpf(var);
        const float Ls = red16_sum(lv);      // sum over d (lane bits 0-3)
        if (d == 0) s_A[cc] = Ls;            // stash L; consumed below
    }
    __syncthreads();

    if (t < NC) {
        const float log2pi16 = 16.0f * 1.8378770664093453f;
        float ar0 = s_r0[0][t] + s_r0[1][t] + s_r0[2][t] + s_r0[3][t];
        const float rs = ar0 + EPSI;
        const float L  = s_A[t];
        const float costsum = rs * (16.0f * rbeta_v + 0.5f * L);
        const float x  = inv_temp * (rbeta_a - costsum);
        const float oa = 1.0f / (1.0f + __expf(-x));
        // last pass: stash oa (the output). otherwise: combined logit base
        s_A[t] = last ? oa : (__logf(oa + EPSI) - 0.5f * (log2pi16 + L));
    }
    __syncthreads();
}

__global__ __launch_bounds__(NT, 2) void convcaps_em_kernel(
    const float* __restrict__ g_act,    // [B,196,32]
    const float* __restrict__ g_pose,   // [B,196,32,16]
    const float* __restrict__ g_W,      // [288,32,16]
    const float* __restrict__ g_beta_a, // [32]
    const float* __restrict__ g_beta_v, // [32]
    const int*   __restrict__ g_cpm,    // [144,9]
    float* __restrict__ g_out)          // act [B*144*32] then pose [B*144*32*16]
{
    __shared__ float s_pose[NK][ND];       // 18432 B
    __shared__ float s_act[NK];            // 1152 B
    __shared__ float s_m1[NRED][NC][ND];   // 8192 B
    __shared__ float s_m2[NRED][NC][ND];   // 8192 B
    __shared__ float s_r0[NRED][NC];       // 512 B
    __shared__ float s_mu[NC][17];         // 2176 B
    __shared__ float s_ivar[NC][17];       // 2176 B
    __shared__ float s_A[NC];              // 128 B   == 40960 B total -> 4 blk/CU

    const int bp   = blockIdx.x;
    const int b    = bp / NP;
    const int p    = bp - b * NP;
    const int t    = threadIdx.x;
    const int c    = t & 31;
    const int s    = t >> 5;
    const int wave = t >> 6;
    const int lane = t & 63;

    float rbeta_a = 0.0f, rbeta_v = 0.0f;
    if (t < NC) { rbeta_a = g_beta_a[t]; rbeta_v = g_beta_v[t]; }

    // ---- gather child poses (float4) + activations into LDS ----
    {
        const int* cpm = g_cpm + p * KW;
        const float4* pb4 = (const float4*)(g_pose + (size_t)b * (196 * CIN * ND));
        float4* sp4 = (float4*)&s_pose[0][0];
        for (int i4 = t; i4 < NK * ND / 4; i4 += NT) {  // 1152 float4
            const int w   = i4 >> 7;                    // 128 float4 per window
            const int rem = i4 & 127;
            sp4[i4] = pb4[(size_t)cpm[w] * 128 + rem];
        }
        const float* ab = g_act + (size_t)b * (196 * CIN);
        if (t < NK) s_act[t] = ab[cpm[t >> 5] * CIN + (t & 31)];
    }
    __syncthreads();

    const int    k0  = s * KPT;
    const float* wp0 = g_W + (size_t)(k0 * NC + c) * ND;

    // ================= pass 0: uniform rr = 1/32 =================
    {
        float r0 = 0.0f, m1[ND], m2[ND];
        #pragma unroll
        for (int d = 0; d < ND; ++d) { m1[d] = 0.0f; m2[d] = 0.0f; }

        const float* wp = wp0;
        for (int j = 0; j < KPT; ++j, wp += NC * ND) {
            const int k = k0 + j;
            float pr[ND], wr[ND], vote[ND];
            load16(&s_pose[k][0], pr);
            load16(wp, wr);
            vote44(pr, wr, vote);

            const float rp = s_act[k] * (1.0f / 32.0f);
            r0 += rp;
            #pragma unroll
            for (int d = 0; d < ND; ++d) {
                const float rv = rp * vote[d];
                m1[d] += rv;
                m2[d] = fmaf(rv, vote[d], m2[d]);
            }
        }
        reduce_finalize(r0, m1, m2, t, c, wave, lane, 1.0f, false, rbeta_a, rbeta_v,
                        s_m1, s_m2, s_r0, s_mu, s_ivar, s_A);
    }

    // ================= passes 1,2: E-step fused into M-step =================
    for (int it = 1; it < 3; ++it) {
        // hoist per-iteration stats: q = sum_d v*(iv*v - 2*iv*mu) + g; fold g into base
        float iv_r[ND], h2n_r[ND];
        float gq = 0.0f;
        #pragma unroll
        for (int d = 0; d < ND; ++d) {
            const float mu = s_mu[c][d];
            const float iv = s_ivar[c][d];
            iv_r[d] = iv;
            const float h = iv * mu;
            h2n_r[d] = -(h + h);
            gq = fmaf(h, mu, gq);
        }
        const float Abase = s_A[c] - 0.5f * gq;

        float r0 = 0.0f, m1[ND], m2[ND];
        #pragma unroll
        for (int d = 0; d < ND; ++d) { m1[d] = 0.0f; m2[d] = 0.0f; }

        const float* wp = wp0;
        for (int j = 0; j < KPT; ++j, wp += NC * ND) {
            const int k = k0 + j;
            float pr[ND], wr[ND], v[ND];
            load16(&s_pose[k][0], pr);
            load16(wp, wr);
            vote44(pr, wr, v);

            float q = 0.0f;
            #pragma unroll
            for (int d = 0; d < ND; ++d) {
                const float tq = fmaf(iv_r[d], v[d], h2n_r[d]);
                q = fmaf(tq, v[d], q);
            }
            const float logit = fmaf(-0.5f, q, Abase);

            // softmax over the 32 c-lanes
            const float mx = red32_max(logit);
            const float e  = __expf(logit - mx);
            const float se = red32_sum(e);

            const float rp = e * __builtin_amdgcn_rcpf(se) * s_act[k];
            r0 += rp;
            #pragma unroll
            for (int d = 0; d < ND; ++d) {
                const float rv = rp * v[d];
                m1[d] += rv;
                m2[d] = fmaf(rv, v[d], m2[d]);
            }
        }
        reduce_finalize(r0, m1, m2, t, c, wave, lane, 1.0f + (float)it, it == 2,
                        rbeta_a, rbeta_v,
                        s_m1, s_m2, s_r0, s_mu, s_ivar, s_A);
    }

    // ---- write outputs: act [B,P,C] then pose [B,P,C,16] ----
    const int base = (b * NP + p) * NC;
    if (t < NC) g_out[base + t] = s_A[t];
    float* outpose = g_out + NB * NP * NC;
    {
        const int cc = t >> 4;
        const int d  = t & 15;
        outpose[(size_t)(base + cc) * ND + d] = s_mu[cc][d];
    }
}

extern "C" void kernel_launch(void* const* d_in, const int* in_sizes, int n_in,
                              void* d_out, int out_size, void* d_ws, size_t ws_size,
                              hipStream_t stream) {
    const float* in_act  = (const float*)d_in[0];
    const float* in_pose = (const float*)d_in[1];
    const float* W       = (const float*)d_in[2];
    const float* beta_a  = (const float*)d_in[3];
    const float* beta_v  = (const float*)d_in[4];
    const int*   cpm     = (const int*)d_in[5];
    float* out = (float*)d_out;

    convcaps_em_kernel<<<dim3(NB * NP), dim3(NT), 0, stream>>>(
        in_act, in_pose, W, beta_a, beta_v, cpm, out);
}

// Round 7
// 111.324 us; speedup vs baseline: 5.3190x; 1.0006x over previous
//
#include <hip/hip_runtime.h>
#include <math.h>

#define NB 4      // batch
#define NP 144    // output spatial positions (12x12)
#define KW 9      // kernel window (3x3)
#define CIN 32
#define NC 32     // output capsules
#define NK 288    // KW*CIN children
#define ND 16     // pose dims
#define EPSI 1e-7f
#define NT 512
#define KPT 18        // k per thread
#define NRED 4        // reduction groups (waves 4-7 write, 0-3 add)

// One block per (b,p). c = t&31, s = t>>5 (k-slice), 18 k per thread.
// LDS = exactly 40960 B; VGPR ~80 -> 3 blocks/CU possible; grid avg 2.25.
// launch_bounds: SINGLE-ARG ONLY. Evidence r2/r3/r5/r6: the 2nd arg acts as
// a waves-per-EU residency cap (r5/r6 (512,2) -> occupancy 17% with 1 blk/CU
// despite LDS/VGPR allowing 3) AND caps VGPR at 256/arg (r3: arg=8 -> 32-reg
// spill disaster; r4: arg=4 -> 64-reg spill).
// Softmax over the 32 c-lanes: DPP for xor1/2/4/8 + one ds_swizzle for xor16;
// E-step logits in exp2 domain (log2e folded into hoisted per-c constants).

template<int CTRL>
__device__ __forceinline__ float dppf(float x) {
    return __int_as_float(__builtin_amdgcn_update_dpp(
        0, __float_as_int(x), CTRL, 0xF, 0xF, true));
}
// 0xB1=quad_perm xor1 ; 0x4E=quad_perm xor2 ; 0x141=row_half_mirror (xor4 once
// 4-uniform) ; 0x140=row_mirror (xor8 once 8-uniform)
__device__ __forceinline__ float swz16(float x) {
    return __int_as_float(__builtin_amdgcn_ds_swizzle(__float_as_int(x), 0x401F));
}
__device__ __forceinline__ float red32_max(float x) {
    x = fmaxf(x, dppf<0xB1>(x));
    x = fmaxf(x, dppf<0x4E>(x));
    x = fmaxf(x, dppf<0x141>(x));
    x = fmaxf(x, dppf<0x140>(x));
    x = fmaxf(x, swz16(x));
    return x;
}
__device__ __forceinline__ float red32_sum(float x) {
    x += dppf<0xB1>(x);
    x += dppf<0x4E>(x);
    x += dppf<0x141>(x);
    x += dppf<0x140>(x);
    x += swz16(x);
    return x;
}
__device__ __forceinline__ float red16_sum(float x) {  // sum over lane bits 0-3
    x += dppf<0xB1>(x);
    x += dppf<0x4E>(x);
    x += dppf<0x141>(x);
    x += dppf<0x140>(x);
    return x;
}

__device__ __forceinline__ int sw4(int c, int j) { return j ^ ((c >> 1) & 3); }

__device__ __forceinline__ void load16(const float* src, float* dst) {
    const float4* s4 = (const float4*)src;
    *(float4*)&dst[0]  = s4[0];
    *(float4*)&dst[4]  = s4[1];
    *(float4*)&dst[8]  = s4[2];
    *(float4*)&dst[12] = s4[3];
}

__device__ __forceinline__ void vote44(const float* pr, const float* wr, float* vote) {
    #pragma unroll
    for (int i = 0; i < 4; ++i) {
        #pragma unroll
        for (int l = 0; l < 4; ++l) {
            float v = pr[i*4+0] * wr[0*4+l];
            v = fmaf(pr[i*4+1], wr[1*4+l], v);
            v = fmaf(pr[i*4+2], wr[2*4+l], v);
            v = fmaf(pr[i*4+3], wr[3*4+l], v);
            vote[i*4+l] = v;
        }
    }
}

__device__ __forceinline__ void reduce_finalize(
    float r0, float m1[ND], float m2[ND],
    int t, int c, int wave, int lane, float inv_temp, bool last,
    float rbeta_a, float rbeta_v,
    float (&s_m1)[NRED][NC][ND], float (&s_m2)[NRED][NC][ND], float (&s_r0)[NRED][NC],
    float (&s_mu)[NC][17], float (&s_ivar)[NC][17], float (&s_A)[NC])
{
    // merge the two k-slices within each wave
    r0 += __shfl_xor(r0, 32);
    #pragma unroll
    for (int d = 0; d < ND; ++d) {
        m1[d] += __shfl_xor(m1[d], 32);
        m2[d] += __shfl_xor(m2[d], 32);
    }
    // stage 1: waves 4-7 write their group (swizzled float4 -> 4-cy b128)
    if (lane < 32 && wave >= NRED) {
        float4* d1 = (float4*)&s_m1[wave - NRED][c][0];
        float4* d2 = (float4*)&s_m2[wave - NRED][c][0];
        #pragma unroll
        for (int j = 0; j < 4; ++j) {
            d1[sw4(c, j)] = *(const float4*)&m1[4*j];
            d2[sw4(c, j)] = *(const float4*)&m2[4*j];
        }
        s_r0[wave - NRED][c] = r0;
    }
    __syncthreads();
    // stage 2: waves 0-3 add into their group
    if (lane < 32 && wave < NRED) {
        float4* d1 = (float4*)&s_m1[wave][c][0];
        float4* d2 = (float4*)&s_m2[wave][c][0];
        #pragma unroll
        for (int j = 0; j < 4; ++j) {
            float4 v1 = d1[sw4(c, j)];
            v1.x += m1[4*j]; v1.y += m1[4*j+1]; v1.z += m1[4*j+2]; v1.w += m1[4*j+3];
            d1[sw4(c, j)] = v1;
            float4 v2 = d2[sw4(c, j)];
            v2.x += m2[4*j]; v2.y += m2[4*j+1]; v2.z += m2[4*j+2]; v2.w += m2[4*j+3];
            d2[sw4(c, j)] = v2;
        }
        s_r0[wave][c] += r0;
    }
    __syncthreads();

    // finalize: each thread owns one (cc,d)  (NT == NC*ND == 512)
    {
        const int cc = t >> 4;
        const int d  = t & 15;
        const int fi = cc * ND + sw4(cc, d >> 2) * 4 + (d & 3);
        float am1 = 0.0f, am2 = 0.0f, ar0 = 0.0f;
        #pragma unroll
        for (int g = 0; g < NRED; ++g) {
            am1 += (&s_m1[g][0][0])[fi];
            am2 += (&s_m2[g][0][0])[fi];
            ar0 += s_r0[g][cc];
        }
        const float rs  = ar0 + EPSI;
        const float irs = __builtin_amdgcn_rcpf(rs);
        const float mu  = am1 * irs;
        // sum rp*(v-mu)^2 = m2 - 2*mu*m1 + mu^2*r0  (exact expansion)
        const float var = (am2 - mu * (2.0f * am1 - mu * ar0)) * irs + EPSI;
        const float lv  = __logf(var);
        s_mu[cc][d]   = mu;
        s_ivar[cc][d] = __builtin_amdgcn_rcpf(var);
        const float Ls = red16_sum(lv);      // sum over d (lane bits 0-3)
        if (d == 0) s_A[cc] = Ls;            // stash L; consumed below
    }
    __syncthreads();

    if (t < NC) {
        const float log2pi16 = 16.0f * 1.8378770664093453f;
        float ar0 = s_r0[0][t] + s_r0[1][t] + s_r0[2][t] + s_r0[3][t];
        const float rs = ar0 + EPSI;
        const float L  = s_A[t];
        const float costsum = rs * (16.0f * rbeta_v + 0.5f * L);
        const float x  = inv_temp * (rbeta_a - costsum);
        const float oa = 1.0f / (1.0f + __expf(-x));
        // last pass: stash oa (the output). otherwise: combined logit base
        s_A[t] = last ? oa : (__logf(oa + EPSI) - 0.5f * (log2pi16 + L));
    }
    __syncthreads();
}

__global__ __launch_bounds__(NT) void convcaps_em_kernel(
    const float* __restrict__ g_act,    // [B,196,32]
    const float* __restrict__ g_pose,   // [B,196,32,16]
    const float* __restrict__ g_W,      // [288,32,16]
    const float* __restrict__ g_beta_a, // [32]
    const float* __restrict__ g_beta_v, // [32]
    const int*   __restrict__ g_cpm,    // [144,9]
    float* __restrict__ g_out)          // act [B*144*32] then pose [B*144*32*16]
{
    __shared__ float s_pose[NK][ND];       // 18432 B
    __shared__ float s_act[NK];            // 1152 B
    __shared__ float s_m1[NRED][NC][ND];   // 8192 B
    __shared__ float s_m2[NRED][NC][ND];   // 8192 B
    __shared__ float s_r0[NRED][NC];       // 512 B
    __shared__ float s_mu[NC][17];         // 2176 B
    __shared__ float s_ivar[NC][17];       // 2176 B
    __shared__ float s_A[NC];              // 128 B   == 40960 B total -> 4 blk/CU

    const int bp   = blockIdx.x;
    const int b    = bp / NP;
    const int p    = bp - b * NP;
    const int t    = threadIdx.x;
    const int c    = t & 31;
    const int s    = t >> 5;
    const int wave = t >> 6;
    const int lane = t & 63;

    float rbeta_a = 0.0f, rbeta_v = 0.0f;
    if (t < NC) { rbeta_a = g_beta_a[t]; rbeta_v = g_beta_v[t]; }

    // ---- gather child poses (float4) + activations into LDS ----
    {
        const int* cpm = g_cpm + p * KW;
        const float4* pb4 = (const float4*)(g_pose + (size_t)b * (196 * CIN * ND));
        float4* sp4 = (float4*)&s_pose[0][0];
        for (int i4 = t; i4 < NK * ND / 4; i4 += NT) {  // 1152 float4
            const int w   = i4 >> 7;                    // 128 float4 per window
            const int rem = i4 & 127;
            sp4[i4] = pb4[(size_t)cpm[w] * 128 + rem];
        }
        const float* ab = g_act + (size_t)b * (196 * CIN);
        if (t < NK) s_act[t] = ab[cpm[t >> 5] * CIN + (t & 31)];
    }
    __syncthreads();

    const int    k0  = s * KPT;
    const float* wp0 = g_W + (size_t)(k0 * NC + c) * ND;

    // ================= pass 0: uniform rr = 1/32 =================
    {
        float r0 = 0.0f, m1[ND], m2[ND];
        #pragma unroll
        for (int d = 0; d < ND; ++d) { m1[d] = 0.0f; m2[d] = 0.0f; }

        const float* wp = wp0;
        for (int j = 0; j < KPT; ++j, wp += NC * ND) {
            const int k = k0 + j;
            float pr[ND], wr[ND], vote[ND];
            load16(&s_pose[k][0], pr);
            load16(wp, wr);
            vote44(pr, wr, vote);

            const float rp = s_act[k] * (1.0f / 32.0f);
            r0 += rp;
            #pragma unroll
            for (int d = 0; d < ND; ++d) {
                const float rv = rp * vote[d];
                m1[d] += rv;
                m2[d] = fmaf(rv, vote[d], m2[d]);
            }
        }
        reduce_finalize(r0, m1, m2, t, c, wave, lane, 1.0f, false, rbeta_a, rbeta_v,
                        s_m1, s_m2, s_r0, s_mu, s_ivar, s_A);
    }

    // ================= passes 1,2: E-step fused into M-step =================
    for (int it = 1; it < 3; ++it) {
        // hoist per-iter stats in exp2 domain: logit2 = A2 - sum_d v*(iv2*v - 2*iv2*mu)
        // where iv2 = 0.5*log2e*ivar. softmax(exp2, logits*log2e) == softmax(exp, logits).
        const float L2E = 1.4426950408889634f;
        float iv2_r[ND], h2n2_r[ND];
        float gq2 = 0.0f;
        #pragma unroll
        for (int d = 0; d < ND; ++d) {
            const float mu  = s_mu[c][d];
            const float iv2 = s_ivar[c][d] * (0.5f * L2E);
            iv2_r[d] = iv2;
            const float h = iv2 * mu;
            h2n2_r[d] = -(h + h);
            gq2 = fmaf(h, mu, gq2);
        }
        const float A2 = fmaf(L2E, s_A[c], -gq2);

        float r0 = 0.0f, m1[ND], m2[ND];
        #pragma unroll
        for (int d = 0; d < ND; ++d) { m1[d] = 0.0f; m2[d] = 0.0f; }

        const float* wp = wp0;
        for (int j = 0; j < KPT; ++j, wp += NC * ND) {
            const int k = k0 + j;
            float pr[ND], wr[ND], v[ND];
            load16(&s_pose[k][0], pr);
            load16(wp, wr);
            vote44(pr, wr, v);

            float q2 = 0.0f;
            #pragma unroll
            for (int d = 0; d < ND; ++d) {
                const float tq = fmaf(iv2_r[d], v[d], h2n2_r[d]);
                q2 = fmaf(tq, v[d], q2);
            }
            const float logit2 = A2 - q2;

            // softmax over the 32 c-lanes (exp2 domain)
            const float mx = red32_max(logit2);
            const float e  = __builtin_amdgcn_exp2f(logit2 - mx);
            const float se = red32_sum(e);

            const float rp = e * __builtin_amdgcn_rcpf(se) * s_act[k];
            r0 += rp;
            #pragma unroll
            for (int d = 0; d < ND; ++d) {
                const float rv = rp * v[d];
                m1[d] += rv;
                m2[d] = fmaf(rv, v[d], m2[d]);
            }
        }
        reduce_finalize(r0, m1, m2, t, c, wave, lane, 1.0f + (float)it, it == 2,
                        rbeta_a, rbeta_v,
                        s_m1, s_m2, s_r0, s_mu, s_ivar, s_A);
    }

    // ---- write outputs: act [B,P,C] then pose [B,P,C,16] ----
    const int base = (b * NP + p) * NC;
    if (t < NC) g_out[base + t] = s_A[t];
    float* outpose = g_out + NB * NP * NC;
    {
        const int cc = t >> 4;
        const int d  = t & 15;
        outpose[(size_t)(base + cc) * ND + d] = s_mu[cc][d];
    }
}

extern "C" void kernel_launch(void* const* d_in, const int* in_sizes, int n_in,
                              void* d_out, int out_size, void* d_ws, size_t ws_size,
                              hipStream_t stream) {
    const float* in_act  = (const float*)d_in[0];
    const float* in_pose = (const float*)d_in[1];
    const float* W       = (const float*)d_in[2];
    const float* beta_a  = (const float*)d_in[3];
    const float* beta_v  = (const float*)d_in[4];
    const int*   cpm     = (const int*)d_in[5];
    float* out = (float*)d_out;

    convcaps_em_kernel<<<dim3(NB * NP), dim3(NT), 0, stream>>>(
        in_act, in_pose, W, beta_a, beta_v, cpm, out);
}

// Round 8
// 102.365 us; speedup vs baseline: 5.7845x; 1.0875x over previous
//
#include <hip/hip_runtime.h>
#include <math.h>

#define NB 4      // batch
#define NP 144    // output spatial positions (12x12)
#define KW 9      // kernel window (3x3)
#define CIN 32
#define NC 32     // output capsules
#define NK 288    // KW*CIN children
#define ND 16     // pose dims
#define EPSI 1e-7f
#define NT 512
#define KPT 18        // k per thread
#define NRED 4        // reduction groups (waves 4-7 write, 0-3 add)

// One block per (b,p). c = t&31, s = t>>5 (k-slice), 18 k per thread.
// KEY CHANGE r8: depth-1 register prefetch of W (unroll-2 ping-pong). At
// VGPR=80 (r5-r7) the compiler streamed W/pose in quads with a waitcnt per
// quad -> ~8 exposed L2-latency waits per k (W always misses L1; W=589KB).
// Prefetching W[k+1] into a dedicated 16-reg buffer while k computes removes
// that latency from the chain. launch_bounds single-arg ONLY (r3/r4: 2nd arg
// caps VGPR at 256/arg -> catastrophic spill).

template<int CTRL>
__device__ __forceinline__ float dppf(float x) {
    return __int_as_float(__builtin_amdgcn_update_dpp(
        0, __float_as_int(x), CTRL, 0xF, 0xF, true));
}
// 0xB1=quad_perm xor1 ; 0x4E=quad_perm xor2 ; 0x141=row_half_mirror (xor4 once
// 4-uniform) ; 0x140=row_mirror (xor8 once 8-uniform)
__device__ __forceinline__ float swz16(float x) {
    return __int_as_float(__builtin_amdgcn_ds_swizzle(__float_as_int(x), 0x401F));
}
__device__ __forceinline__ float red32_max(float x) {
    x = fmaxf(x, dppf<0xB1>(x));
    x = fmaxf(x, dppf<0x4E>(x));
    x = fmaxf(x, dppf<0x141>(x));
    x = fmaxf(x, dppf<0x140>(x));
    x = fmaxf(x, swz16(x));
    return x;
}
__device__ __forceinline__ float red32_sum(float x) {
    x += dppf<0xB1>(x);
    x += dppf<0x4E>(x);
    x += dppf<0x141>(x);
    x += dppf<0x140>(x);
    x += swz16(x);
    return x;
}
__device__ __forceinline__ float red16_sum(float x) {  // sum over lane bits 0-3
    x += dppf<0xB1>(x);
    x += dppf<0x4E>(x);
    x += dppf<0x141>(x);
    x += dppf<0x140>(x);
    return x;
}

__device__ __forceinline__ int sw4(int c, int j) { return j ^ ((c >> 1) & 3); }

__device__ __forceinline__ void load16(const float* src, float* dst) {
    const float4* s4 = (const float4*)src;
    *(float4*)&dst[0]  = s4[0];
    *(float4*)&dst[4]  = s4[1];
    *(float4*)&dst[8]  = s4[2];
    *(float4*)&dst[12] = s4[3];
}

__device__ __forceinline__ void vote44(const float* pr, const float* wr, float* vote) {
    #pragma unroll
    for (int i = 0; i < 4; ++i) {
        #pragma unroll
        for (int l = 0; l < 4; ++l) {
            float v = pr[i*4+0] * wr[0*4+l];
            v = fmaf(pr[i*4+1], wr[1*4+l], v);
            v = fmaf(pr[i*4+2], wr[2*4+l], v);
            v = fmaf(pr[i*4+3], wr[3*4+l], v);
            vote[i*4+l] = v;
        }
    }
}

// E-step + M-accumulate for one (k, c) given the vote in registers
__device__ __forceinline__ void estep_body(
    const float v[ND], float actk,
    const float iv2_r[ND], const float h2n2_r[ND], float A2,
    float& r0, float m1[ND], float m2[ND])
{
    float qa = 0.0f, qb = 0.0f;           // two 8-deep chains instead of one 16-deep
    #pragma unroll
    for (int d = 0; d < ND; d += 2) {
        qa = fmaf(fmaf(iv2_r[d],   v[d],   h2n2_r[d]),   v[d],   qa);
        qb = fmaf(fmaf(iv2_r[d+1], v[d+1], h2n2_r[d+1]), v[d+1], qb);
    }
    const float logit2 = A2 - (qa + qb);
    const float mx = red32_max(logit2);
    const float e  = __builtin_amdgcn_exp2f(logit2 - mx);
    const float se = red32_sum(e);
    const float rp = e * __builtin_amdgcn_rcpf(se) * actk;
    r0 += rp;
    #pragma unroll
    for (int d = 0; d < ND; ++d) {
        const float rv = rp * v[d];
        m1[d] += rv;
        m2[d] = fmaf(rv, v[d], m2[d]);
    }
}

__device__ __forceinline__ void pass0_body(
    const float v[ND], float actk,
    float& r0, float m1[ND], float m2[ND])
{
    const float rp = actk * (1.0f / 32.0f);
    r0 += rp;
    #pragma unroll
    for (int d = 0; d < ND; ++d) {
        const float rv = rp * v[d];
        m1[d] += rv;
        m2[d] = fmaf(rv, v[d], m2[d]);
    }
}

__device__ __forceinline__ void reduce_finalize(
    float r0, float m1[ND], float m2[ND],
    int t, int c, int wave, int lane, float inv_temp, bool last,
    float rbeta_a, float rbeta_v,
    float (&s_m1)[NRED][NC][ND], float (&s_m2)[NRED][NC][ND], float (&s_r0)[NRED][NC],
    float (&s_mu)[NC][17], float (&s_ivar)[NC][17], float (&s_A)[NC])
{
    // merge the two k-slices within each wave
    r0 += __shfl_xor(r0, 32);
    #pragma unroll
    for (int d = 0; d < ND; ++d) {
        m1[d] += __shfl_xor(m1[d], 32);
        m2[d] += __shfl_xor(m2[d], 32);
    }
    // stage 1: waves 4-7 write their group (swizzled float4 -> conflict-free)
    if (lane < 32 && wave >= NRED) {
        float4* d1 = (float4*)&s_m1[wave - NRED][c][0];
        float4* d2 = (float4*)&s_m2[wave - NRED][c][0];
        #pragma unroll
        for (int j = 0; j < 4; ++j) {
            d1[sw4(c, j)] = *(const float4*)&m1[4*j];
            d2[sw4(c, j)] = *(const float4*)&m2[4*j];
        }
        s_r0[wave - NRED][c] = r0;
    }
    __syncthreads();
    // stage 2: waves 0-3 add into their group
    if (lane < 32 && wave < NRED) {
        float4* d1 = (float4*)&s_m1[wave][c][0];
        float4* d2 = (float4*)&s_m2[wave][c][0];
        #pragma unroll
        for (int j = 0; j < 4; ++j) {
            float4 v1 = d1[sw4(c, j)];
            v1.x += m1[4*j]; v1.y += m1[4*j+1]; v1.z += m1[4*j+2]; v1.w += m1[4*j+3];
            d1[sw4(c, j)] = v1;
            float4 v2 = d2[sw4(c, j)];
            v2.x += m2[4*j]; v2.y += m2[4*j+1]; v2.z += m2[4*j+2]; v2.w += m2[4*j+3];
            d2[sw4(c, j)] = v2;
        }
        s_r0[wave][c] += r0;
    }
    __syncthreads();

    // finalize: each thread owns one (cc,d)  (NT == NC*ND == 512)
    {
        const int cc = t >> 4;
        const int d  = t & 15;
        const int fi = cc * ND + sw4(cc, d >> 2) * 4 + (d & 3);
        float am1 = 0.0f, am2 = 0.0f, ar0 = 0.0f;
        #pragma unroll
        for (int g = 0; g < NRED; ++g) {
            am1 += (&s_m1[g][0][0])[fi];
            am2 += (&s_m2[g][0][0])[fi];
            ar0 += s_r0[g][cc];
        }
        const float rs  = ar0 + EPSI;
        const float irs = __builtin_amdgcn_rcpf(rs);
        const float mu  = am1 * irs;
        // sum rp*(v-mu)^2 = m2 - 2*mu*m1 + mu^2*r0  (exact expansion)
        const float var = (am2 - mu * (2.0f * am1 - mu * ar0)) * irs + EPSI;
        const float lv  = __logf(var);
        s_mu[cc][d]   = mu;
        s_ivar[cc][d] = __builtin_amdgcn_rcpf(var);
        const float Ls = red16_sum(lv);      // sum over d (lane bits 0-3)
        if (d == 0) s_A[cc] = Ls;            // stash L; consumed below
    }
    __syncthreads();

    if (t < NC) {
        const float log2pi16 = 16.0f * 1.8378770664093453f;
        float ar0 = s_r0[0][t] + s_r0[1][t] + s_r0[2][t] + s_r0[3][t];
        const float rs = ar0 + EPSI;
        const float L  = s_A[t];
        const float costsum = rs * (16.0f * rbeta_v + 0.5f * L);
        const float x  = inv_temp * (rbeta_a - costsum);
        const float oa = 1.0f / (1.0f + __expf(-x));
        // last pass: stash oa (the output). otherwise: combined logit base
        s_A[t] = last ? oa : (__logf(oa + EPSI) - 0.5f * (log2pi16 + L));
    }
    __syncthreads();
}

__global__ __launch_bounds__(NT) void convcaps_em_kernel(
    const float* __restrict__ g_act,    // [B,196,32]
    const float* __restrict__ g_pose,   // [B,196,32,16]
    const float* __restrict__ g_W,      // [288,32,16]
    const float* __restrict__ g_beta_a, // [32]
    const float* __restrict__ g_beta_v, // [32]
    const int*   __restrict__ g_cpm,    // [144,9]
    float* __restrict__ g_out)          // act [B*144*32] then pose [B*144*32*16]
{
    __shared__ float s_pose[NK][ND];       // 18432 B
    __shared__ float s_act[NK];            // 1152 B
    __shared__ float s_m1[NRED][NC][ND];   // 8192 B
    __shared__ float s_m2[NRED][NC][ND];   // 8192 B
    __shared__ float s_r0[NRED][NC];       // 512 B
    __shared__ float s_mu[NC][17];         // 2176 B
    __shared__ float s_ivar[NC][17];       // 2176 B
    __shared__ float s_A[NC];              // 128 B   == 40960 B total

    const int bp   = blockIdx.x;
    const int b    = bp / NP;
    const int p    = bp - b * NP;
    const int t    = threadIdx.x;
    const int c    = t & 31;
    const int s    = t >> 5;
    const int wave = t >> 6;
    const int lane = t & 63;

    float rbeta_a = 0.0f, rbeta_v = 0.0f;
    if (t < NC) { rbeta_a = g_beta_a[t]; rbeta_v = g_beta_v[t]; }

    // ---- gather child poses (float4) + activations into LDS ----
    {
        const int* cpm = g_cpm + p * KW;
        const float4* pb4 = (const float4*)(g_pose + (size_t)b * (196 * CIN * ND));
        float4* sp4 = (float4*)&s_pose[0][0];
        for (int i4 = t; i4 < NK * ND / 4; i4 += NT) {  // 1152 float4
            const int w   = i4 >> 7;                    // 128 float4 per window
            const int rem = i4 & 127;
            sp4[i4] = pb4[(size_t)cpm[w] * 128 + rem];
        }
        const float* ab = g_act + (size_t)b * (196 * CIN);
        if (t < NK) s_act[t] = ab[cpm[t >> 5] * CIN + (t & 31)];
    }
    __syncthreads();

    const int    k0  = s * KPT;
    const float* wp0 = g_W + (size_t)(k0 * NC + c) * ND;

    // ================= pass 0: uniform rr = 1/32 (W prefetched) =================
    {
        float r0 = 0.0f, m1[ND], m2[ND];
        #pragma unroll
        for (int d = 0; d < ND; ++d) { m1[d] = 0.0f; m2[d] = 0.0f; }

        float wrA[ND], wrB[ND];
        load16(wp0, wrA);
        for (int jj = 0; jj < KPT; jj += 2) {
            // prefetch k = jj+1 while computing jj
            load16(wp0 + (size_t)(jj + 1) * (NC * ND), wrB);
            {
                const float actk = s_act[k0 + jj];
                float pr[ND], v[ND];
                load16(&s_pose[k0 + jj][0], pr);
                vote44(pr, wrA, v);
                pass0_body(v, actk, r0, m1, m2);
            }
            // prefetch next even k (clamped re-load on the last trip; unused)
            const int jn = (jj + 2 < KPT) ? (jj + 2) : (KPT - 1);
            load16(wp0 + (size_t)jn * (NC * ND), wrA);
            {
                const float actk = s_act[k0 + jj + 1];
                float pr[ND], v[ND];
                load16(&s_pose[k0 + jj + 1][0], pr);
                vote44(pr, wrB, v);
                pass0_body(v, actk, r0, m1, m2);
            }
        }
        reduce_finalize(r0, m1, m2, t, c, wave, lane, 1.0f, false, rbeta_a, rbeta_v,
                        s_m1, s_m2, s_r0, s_mu, s_ivar, s_A);
    }

    // ================= passes 1,2: E-step fused into M-step =================
    for (int it = 1; it < 3; ++it) {
        // hoist per-iter stats in exp2 domain: logit2 = A2 - sum_d v*(iv2*v - 2*iv2*mu)
        const float L2E = 1.4426950408889634f;
        float iv2_r[ND], h2n2_r[ND];
        float gq2 = 0.0f;
        #pragma unroll
        for (int d = 0; d < ND; ++d) {
            const float mu  = s_mu[c][d];
            const float iv2 = s_ivar[c][d] * (0.5f * L2E);
            iv2_r[d] = iv2;
            const float h = iv2 * mu;
            h2n2_r[d] = -(h + h);
            gq2 = fmaf(h, mu, gq2);
        }
        const float A2 = fmaf(L2E, s_A[c], -gq2);

        float r0 = 0.0f, m1[ND], m2[ND];
        #pragma unroll
        for (int d = 0; d < ND; ++d) { m1[d] = 0.0f; m2[d] = 0.0f; }

        float wrA[ND], wrB[ND];
        load16(wp0, wrA);
        for (int jj = 0; jj < KPT; jj += 2) {
            // prefetch k = jj+1 while computing jj
            load16(wp0 + (size_t)(jj + 1) * (NC * ND), wrB);
            {
                const float actk = s_act[k0 + jj];
                float pr[ND], v[ND];
                load16(&s_pose[k0 + jj][0], pr);
                vote44(pr, wrA, v);
                estep_body(v, actk, iv2_r, h2n2_r, A2, r0, m1, m2);
            }
            // prefetch next even k (clamped re-load on the last trip; unused)
            const int jn = (jj + 2 < KPT) ? (jj + 2) : (KPT - 1);
            load16(wp0 + (size_t)jn * (NC * ND), wrA);
            {
                const float actk = s_act[k0 + jj + 1];
                float pr[ND], v[ND];
                load16(&s_pose[k0 + jj + 1][0], pr);
                vote44(pr, wrB, v);
                estep_body(v, actk, iv2_r, h2n2_r, A2, r0, m1, m2);
            }
        }
        reduce_finalize(r0, m1, m2, t, c, wave, lane, 1.0f + (float)it, it == 2,
                        rbeta_a, rbeta_v,
                        s_m1, s_m2, s_r0, s_mu, s_ivar, s_A);
    }

    // ---- write outputs: act [B,P,C] then pose [B,P,C,16] ----
    const int base = (b * NP + p) * NC;
    if (t < NC) g_out[base + t] = s_A[t];
    float* outpose = g_out + NB * NP * NC;
    {
        const int cc = t >> 4;
        const int d  = t & 15;
        outpose[(size_t)(base + cc) * ND + d] = s_mu[cc][d];
    }
}

extern "C" void kernel_launch(void* const* d_in, const int* in_sizes, int n_in,
                              void* d_out, int out_size, void* d_ws, size_t ws_size,
                              hipStream_t stream) {
    const float* in_act  = (const float*)d_in[0];
    const float* in_pose = (const float*)d_in[1];
    const float* W       = (const float*)d_in[2];
    const float* beta_a  = (const float*)d_in[3];
    const float* beta_v  = (const float*)d_in[4];
    const int*   cpm     = (const int*)d_in[5];
    float* out = (float*)d_out;

    convcaps_em_kernel<<<dim3(NB * NP), dim3(NT), 0, stream>>>(
        in_act, in_pose, W, beta_a, beta_v, cpm, out);
}

// Round 9
// 101.060 us; speedup vs baseline: 5.8592x; 1.0129x over previous
//
#include <hip/hip_runtime.h>
#include <math.h>

#define NB 4      // batch
#define NP 144    // output spatial positions (12x12)
#define KW 9      // kernel window (3x3)
#define CIN 32
#define NC 32     // output capsules
#define NK 288    // KW*CIN children
#define ND 16     // pose dims
#define NDH 8     // ND/2 (packed float2)
#define EPSI 1e-7f
#define NT 512
#define KPT 18        // k per thread
#define NRED 4        // reduction groups (waves 4-7 write, 0-3 add)

// One block per (b,p). c = t&31, s = t>>5 (k-slice), 18 k per thread.
// KEY CHANGE r9: all d-indexed math (vote 4x4, q2, m1/m2 accumulation) in
// packed float2 (ext_vector_type) to emit v_pk_fma_f32 — 2 FP32 FMA/instr.
// Scalar-FMA streams were ~144 of ~165 VALU instr/visit; packing halves them.
// Keeps r8: depth-1 W register prefetch (VGPR 112, no spill), DPP softmax
// (xor1/2/4/8 on VALU pipe + one ds_swizzle for xor16), exp2-domain E-step.
// launch_bounds single-arg ONLY (r3/r4: 2nd arg caps VGPR at 256/arg -> spill).

typedef float v2f __attribute__((ext_vector_type(2)));

__device__ __forceinline__ v2f mkv2(float a, float b) { v2f r; r[0] = a; r[1] = b; return r; }

template<int CTRL>
__device__ __forceinline__ float dppf(float x) {
    return __int_as_float(__builtin_amdgcn_update_dpp(
        0, __float_as_int(x), CTRL, 0xF, 0xF, true));
}
// 0xB1=quad_perm xor1 ; 0x4E=quad_perm xor2 ; 0x141=row_half_mirror (xor4 once
// 4-uniform) ; 0x140=row_mirror (xor8 once 8-uniform)
__device__ __forceinline__ float swz16(float x) {
    return __int_as_float(__builtin_amdgcn_ds_swizzle(__float_as_int(x), 0x401F));
}
__device__ __forceinline__ float red32_max(float x) {
    x = fmaxf(x, dppf<0xB1>(x));
    x = fmaxf(x, dppf<0x4E>(x));
    x = fmaxf(x, dppf<0x141>(x));
    x = fmaxf(x, dppf<0x140>(x));
    x = fmaxf(x, swz16(x));
    return x;
}
__device__ __forceinline__ float red32_sum(float x) {
    x += dppf<0xB1>(x);
    x += dppf<0x4E>(x);
    x += dppf<0x141>(x);
    x += dppf<0x140>(x);
    x += swz16(x);
    return x;
}
__device__ __forceinline__ float red16_sum(float x) {  // sum over lane bits 0-3
    x += dppf<0xB1>(x);
    x += dppf<0x4E>(x);
    x += dppf<0x141>(x);
    x += dppf<0x140>(x);
    return x;
}

__device__ __forceinline__ int sw4(int c, int j) { return j ^ ((c >> 1) & 3); }

__device__ __forceinline__ void load16(const float* src, float* dst) {
    const float4* s4 = (const float4*)src;
    *(float4*)&dst[0]  = s4[0];
    *(float4*)&dst[4]  = s4[1];
    *(float4*)&dst[8]  = s4[2];
    *(float4*)&dst[12] = s4[3];
}
// 16B loads, repacked into 8 float2 register pairs
__device__ __forceinline__ void load16v(const float* src, v2f* dst) {
    const float4* s4 = (const float4*)src;
    #pragma unroll
    for (int q = 0; q < 4; ++q) {
        const float4 tq = s4[q];
        dst[q*2+0] = mkv2(tq.x, tq.y);
        dst[q*2+1] = mkv2(tq.z, tq.w);
    }
}

// vote pairs over l: v2[i*2+p] = {vote[i*4+2p], vote[i*4+2p+1]} == d-pair 2e,2e+1
__device__ __forceinline__ void vote44v(const float* pr, const v2f* wr2, v2f* v2) {
    #pragma unroll
    for (int i = 0; i < 4; ++i) {
        const v2f p0 = mkv2(pr[i*4+0], pr[i*4+0]);
        const v2f p1 = mkv2(pr[i*4+1], pr[i*4+1]);
        const v2f p2 = mkv2(pr[i*4+2], pr[i*4+2]);
        const v2f p3 = mkv2(pr[i*4+3], pr[i*4+3]);
        #pragma unroll
        for (int p = 0; p < 2; ++p) {
            v2f acc = p0 * wr2[0*2+p];
            acc += p1 * wr2[1*2+p];
            acc += p2 * wr2[2*2+p];
            acc += p3 * wr2[3*2+p];
            v2[i*2+p] = acc;
        }
    }
}

// E-step + M-accumulate for one (k, c), packed
__device__ __forceinline__ void estep_body(
    const v2f v2[NDH], float actk,
    const v2f iv2v[NDH], const v2f h2n2v[NDH], float A2,
    float& r0, v2f m1v[NDH], v2f m2v[NDH])
{
    v2f q2v = mkv2(0.0f, 0.0f);
    #pragma unroll
    for (int e = 0; e < NDH; ++e)
        q2v += (iv2v[e] * v2[e] + h2n2v[e]) * v2[e];
    const float logit2 = A2 - (q2v[0] + q2v[1]);

    const float mx = red32_max(logit2);
    const float e  = __builtin_amdgcn_exp2f(logit2 - mx);
    const float se = red32_sum(e);
    const float rp = e * __builtin_amdgcn_rcpf(se) * actk;
    r0 += rp;
    const v2f rpv = mkv2(rp, rp);
    #pragma unroll
    for (int d = 0; d < NDH; ++d) {
        const v2f rv = rpv * v2[d];
        m1v[d] += rv;
        m2v[d] += rv * v2[d];
    }
}

__device__ __forceinline__ void pass0_body(
    const v2f v2[NDH], float actk,
    float& r0, v2f m1v[NDH], v2f m2v[NDH])
{
    const float rp = actk * (1.0f / 32.0f);
    r0 += rp;
    const v2f rpv = mkv2(rp, rp);
    #pragma unroll
    for (int d = 0; d < NDH; ++d) {
        const v2f rv = rpv * v2[d];
        m1v[d] += rv;
        m2v[d] += rv * v2[d];
    }
}

__device__ __forceinline__ void reduce_finalize(
    float r0, float m1[ND], float m2[ND],
    int t, int c, int wave, int lane, float inv_temp, bool last,
    float rbeta_a, float rbeta_v,
    float (&s_m1)[NRED][NC][ND], float (&s_m2)[NRED][NC][ND], float (&s_r0)[NRED][NC],
    float (&s_mu)[NC][17], float (&s_ivar)[NC][17], float (&s_A)[NC])
{
    // merge the two k-slices within each wave
    r0 += __shfl_xor(r0, 32);
    #pragma unroll
    for (int d = 0; d < ND; ++d) {
        m1[d] += __shfl_xor(m1[d], 32);
        m2[d] += __shfl_xor(m2[d], 32);
    }
    // stage 1: waves 4-7 write their group (swizzled float4 -> conflict-free)
    if (lane < 32 && wave >= NRED) {
        float4* d1 = (float4*)&s_m1[wave - NRED][c][0];
        float4* d2 = (float4*)&s_m2[wave - NRED][c][0];
        #pragma unroll
        for (int j = 0; j < 4; ++j) {
            d1[sw4(c, j)] = *(const float4*)&m1[4*j];
            d2[sw4(c, j)] = *(const float4*)&m2[4*j];
        }
        s_r0[wave - NRED][c] = r0;
    }
    __syncthreads();
    // stage 2: waves 0-3 add into their group
    if (lane < 32 && wave < NRED) {
        float4* d1 = (float4*)&s_m1[wave][c][0];
        float4* d2 = (float4*)&s_m2[wave][c][0];
        #pragma unroll
        for (int j = 0; j < 4; ++j) {
            float4 v1 = d1[sw4(c, j)];
            v1.x += m1[4*j]; v1.y += m1[4*j+1]; v1.z += m1[4*j+2]; v1.w += m1[4*j+3];
            d1[sw4(c, j)] = v1;
            float4 v2 = d2[sw4(c, j)];
            v2.x += m2[4*j]; v2.y += m2[4*j+1]; v2.z += m2[4*j+2]; v2.w += m2[4*j+3];
            d2[sw4(c, j)] = v2;
        }
        s_r0[wave][c] += r0;
    }
    __syncthreads();

    // finalize: each thread owns one (cc,d)  (NT == NC*ND == 512)
    {
        const int cc = t >> 4;
        const int d  = t & 15;
        const int fi = cc * ND + sw4(cc, d >> 2) * 4 + (d & 3);
        float am1 = 0.0f, am2 = 0.0f, ar0 = 0.0f;
        #pragma unroll
        for (int g = 0; g < NRED; ++g) {
            am1 += (&s_m1[g][0][0])[fi];
            am2 += (&s_m2[g][0][0])[fi];
            ar0 += s_r0[g][cc];
        }
        const float rs  = ar0 + EPSI;
        const float irs = __builtin_amdgcn_rcpf(rs);
        const float mu  = am1 * irs;
        // sum rp*(v-mu)^2 = m2 - 2*mu*m1 + mu^2*r0  (exact expansion)
        const float var = (am2 - mu * (2.0f * am1 - mu * ar0)) * irs + EPSI;
        const float lv  = __logf(var);
        s_mu[cc][d]   = mu;
        s_ivar[cc][d] = __builtin_amdgcn_rcpf(var);
        const float Ls = red16_sum(lv);      // sum over d (lane bits 0-3)
        if (d == 0) s_A[cc] = Ls;            // stash L; consumed below
    }
    __syncthreads();

    if (t < NC) {
        const float log2pi16 = 16.0f * 1.8378770664093453f;
        float ar0 = s_r0[0][t] + s_r0[1][t] + s_r0[2][t] + s_r0[3][t];
        const float rs = ar0 + EPSI;
        const float L  = s_A[t];
        const float costsum = rs * (16.0f * rbeta_v + 0.5f * L);
        const float x  = inv_temp * (rbeta_a - costsum);
        const float oa = 1.0f / (1.0f + __expf(-x));
        // last pass: stash oa (the output). otherwise: combined logit base
        s_A[t] = last ? oa : (__logf(oa + EPSI) - 0.5f * (log2pi16 + L));
    }
    __syncthreads();
}

__global__ __launch_bounds__(NT) void convcaps_em_kernel(
    const float* __restrict__ g_act,    // [B,196,32]
    const float* __restrict__ g_pose,   // [B,196,32,16]
    const float* __restrict__ g_W,      // [288,32,16]
    const float* __restrict__ g_beta_a, // [32]
    const float* __restrict__ g_beta_v, // [32]
    const int*   __restrict__ g_cpm,    // [144,9]
    float* __restrict__ g_out)          // act [B*144*32] then pose [B*144*32*16]
{
    __shared__ float s_pose[NK][ND];       // 18432 B
    __shared__ float s_act[NK];            // 1152 B
    __shared__ float s_m1[NRED][NC][ND];   // 8192 B
    __shared__ float s_m2[NRED][NC][ND];   // 8192 B
    __shared__ float s_r0[NRED][NC];       // 512 B
    __shared__ float s_mu[NC][17];         // 2176 B
    __shared__ float s_ivar[NC][17];       // 2176 B
    __shared__ float s_A[NC];              // 128 B   == 40960 B total

    const int bp   = blockIdx.x;
    const int b    = bp / NP;
    const int p    = bp - b * NP;
    const int t    = threadIdx.x;
    const int c    = t & 31;
    const int s    = t >> 5;
    const int wave = t >> 6;
    const int lane = t & 63;

    float rbeta_a = 0.0f, rbeta_v = 0.0f;
    if (t < NC) { rbeta_a = g_beta_a[t]; rbeta_v = g_beta_v[t]; }

    // ---- gather child poses (float4) + activations into LDS ----
    {
        const int* cpm = g_cpm + p * KW;
        const float4* pb4 = (const float4*)(g_pose + (size_t)b * (196 * CIN * ND));
        float4* sp4 = (float4*)&s_pose[0][0];
        for (int i4 = t; i4 < NK * ND / 4; i4 += NT) {  // 1152 float4
            const int w   = i4 >> 7;                    // 128 float4 per window
            const int rem = i4 & 127;
            sp4[i4] = pb4[(size_t)cpm[w] * 128 + rem];
        }
        const float* ab = g_act + (size_t)b * (196 * CIN);
        if (t < NK) s_act[t] = ab[cpm[t >> 5] * CIN + (t & 31)];
    }
    __syncthreads();

    const int    k0  = s * KPT;
    const float* wp0 = g_W + (size_t)(k0 * NC + c) * ND;

    // ================= pass 0: uniform rr = 1/32 (W prefetched) =================
    {
        float r0 = 0.0f;
        v2f m1v[NDH], m2v[NDH];
        #pragma unroll
        for (int d = 0; d < NDH; ++d) { m1v[d] = mkv2(0,0); m2v[d] = mkv2(0,0); }

        v2f wrA[NDH], wrB[NDH];
        load16v(wp0, wrA);
        for (int jj = 0; jj < KPT; jj += 2) {
            load16v(wp0 + (size_t)(jj + 1) * (NC * ND), wrB);
            {
                const float actk = s_act[k0 + jj];
                float pr[ND]; v2f v2[NDH];
                load16(&s_pose[k0 + jj][0], pr);
                vote44v(pr, wrA, v2);
                pass0_body(v2, actk, r0, m1v, m2v);
            }
            const int jn = (jj + 2 < KPT) ? (jj + 2) : (KPT - 1);
            load16v(wp0 + (size_t)jn * (NC * ND), wrA);
            {
                const float actk = s_act[k0 + jj + 1];
                float pr[ND]; v2f v2[NDH];
                load16(&s_pose[k0 + jj + 1][0], pr);
                vote44v(pr, wrB, v2);
                pass0_body(v2, actk, r0, m1v, m2v);
            }
        }
        float m1[ND], m2[ND];
        #pragma unroll
        for (int e = 0; e < NDH; ++e) {
            m1[2*e] = m1v[e][0]; m1[2*e+1] = m1v[e][1];
            m2[2*e] = m2v[e][0]; m2[2*e+1] = m2v[e][1];
        }
        reduce_finalize(r0, m1, m2, t, c, wave, lane, 1.0f, false, rbeta_a, rbeta_v,
                        s_m1, s_m2, s_r0, s_mu, s_ivar, s_A);
    }

    // ================= passes 1,2: E-step fused into M-step =================
    for (int it = 1; it < 3; ++it) {
        // hoist per-iter stats in exp2 domain: logit2 = A2 - sum_d v*(iv2*v - 2*iv2*mu)
        const float L2E = 1.4426950408889634f;
        v2f iv2v[NDH], h2n2v[NDH];
        float gq2 = 0.0f;
        #pragma unroll
        for (int e = 0; e < NDH; ++e) {
            float ivs[2], hns[2];
            #pragma unroll
            for (int u = 0; u < 2; ++u) {
                const float mu  = s_mu[c][2*e+u];
                const float iv2 = s_ivar[c][2*e+u] * (0.5f * L2E);
                ivs[u] = iv2;
                const float h = iv2 * mu;
                hns[u] = -(h + h);
                gq2 = fmaf(h, mu, gq2);
            }
            iv2v[e]  = mkv2(ivs[0], ivs[1]);
            h2n2v[e] = mkv2(hns[0], hns[1]);
        }
        const float A2 = fmaf(L2E, s_A[c], -gq2);

        float r0 = 0.0f;
        v2f m1v[NDH], m2v[NDH];
        #pragma unroll
        for (int d = 0; d < NDH; ++d) { m1v[d] = mkv2(0,0); m2v[d] = mkv2(0,0); }

        v2f wrA[NDH], wrB[NDH];
        load16v(wp0, wrA);
        for (int jj = 0; jj < KPT; jj += 2) {
            load16v(wp0 + (size_t)(jj + 1) * (NC * ND), wrB);
            {
                const float actk = s_act[k0 + jj];
                float pr[ND]; v2f v2[NDH];
                load16(&s_pose[k0 + jj][0], pr);
                vote44v(pr, wrA, v2);
                estep_body(v2, actk, iv2v, h2n2v, A2, r0, m1v, m2v);
            }
            const int jn = (jj + 2 < KPT) ? (jj + 2) : (KPT - 1);
            load16v(wp0 + (size_t)jn * (NC * ND), wrA);
            {
                const float actk = s_act[k0 + jj + 1];
                float pr[ND]; v2f v2[NDH];
                load16(&s_pose[k0 + jj + 1][0], pr);
                vote44v(pr, wrB, v2);
                estep_body(v2, actk, iv2v, h2n2v, A2, r0, m1v, m2v);
            }
        }
        float m1[ND], m2[ND];
        #pragma unroll
        for (int e = 0; e < NDH; ++e) {
            m1[2*e] = m1v[e][0]; m1[2*e+1] = m1v[e][1];
            m2[2*e] = m2v[e][0]; m2[2*e+1] = m2v[e][1];
        }
        reduce_finalize(r0, m1, m2, t, c, wave, lane, 1.0f + (float)it, it == 2,
                        rbeta_a, rbeta_v,
                        s_m1, s_m2, s_r0, s_mu, s_ivar, s_A);
    }

    // ---- write outputs: act [B,P,C] then pose [B,P,C,16] ----
    const int base = (b * NP + p) * NC;
    if (t < NC) g_out[base + t] = s_A[t];
    float* outpose = g_out + NB * NP * NC;
    {
        const int cc = t >> 4;
        const int d  = t & 15;
        outpose[(size_t)(base + cc) * ND + d] = s_mu[cc][d];
    }
}

extern "C" void kernel_launch(void* const* d_in, const int* in_sizes, int n_in,
                              void* d_out, int out_size, void* d_ws, size_t ws_size,
                              hipStream_t stream) {
    const float* in_act  = (const float*)d_in[0];
    const float* in_pose = (const float*)d_in[1];
    const float* W       = (const float*)d_in[2];
    const float* beta_a  = (const float*)d_in[3];
    const float* beta_v  = (const float*)d_in[4];
    const int*   cpm     = (const int*)d_in[5];
    float* out = (float*)d_out;

    convcaps_em_kernel<<<dim3(NB * NP), dim3(NT), 0, stream>>>(
        in_act, in_pose, W, beta_a, beta_v, cpm, out);
}